// Round 11
// baseline (2788.348 us; speedup 1.0000x reference)
//
#include <hip/hip_runtime.h>
#include <math.h>

#define NT 256
#define NBLK 512
#define APITCH 40

typedef __attribute__((ext_vector_type(8))) short short8;
typedef __attribute__((ext_vector_type(4))) float f32x4;
typedef unsigned short ushort_t;

__device__ __forceinline__ float sigmoidf_(float x){ return 1.0f/(1.0f+__expf(-x)); }
__device__ __forceinline__ ushort_t f2bf(float x){
  unsigned int u = __float_as_uint(x);
  u = u + 0x7fff + ((u>>16)&1);
  return (ushort_t)(u>>16);
}
__device__ __forceinline__ float bf2f(ushort_t b){
  return __uint_as_float(((unsigned int)b)<<16);
}

// Grid barrier: arrive/depart counters per slot, self-resetting (replay-safe).
// Guaranteed co-residency: __launch_bounds__(256,2) => >=2 blocks/CU capacity,
// 512 blocks <= 2*256. Agent-scope release/acquire atomics handle cross-XCD L2.
__device__ __forceinline__ void gbar(unsigned* bar, int idx, int t){
  __syncthreads();
  if (t == 0){
    unsigned* a = bar + idx*2;
    __hip_atomic_fetch_add(a, 1u, __ATOMIC_RELEASE, __HIP_MEMORY_SCOPE_AGENT);
    while (__hip_atomic_load(a, __ATOMIC_ACQUIRE, __HIP_MEMORY_SCOPE_AGENT) < (unsigned)NBLK)
      __builtin_amdgcn_s_sleep(2);
    unsigned d = __hip_atomic_fetch_add(a+1, 1u, __ATOMIC_ACQ_REL, __HIP_MEMORY_SCOPE_AGENT);
    if (d == (unsigned)NBLK-1u){
      __hip_atomic_store(a,   0u, __ATOMIC_RELAXED, __HIP_MEMORY_SCOPE_AGENT);
      __hip_atomic_store(a+1, 0u, __ATOMIC_RELAXED, __HIP_MEMORY_SCOPE_AGENT);
    }
  }
  __syncthreads();
  __threadfence();   // per-wave L1 invalidate so all waves see remote writes
}

__global__ __launch_bounds__(256, 2) void k_mega(
    const float* __restrict__ jets, const float* __restrict__ W_emb,
    const float* __restrict__ b_emb, const float* __restrict__ w_edge,
    const float* __restrict__ W_msg, const float* __restrict__ b_msg,
    const float* __restrict__ Wi, const float* __restrict__ bi,
    const float* __restrict__ Wh, const float* __restrict__ bh,
    const float* __restrict__ Wr1, const float* __restrict__ br1,
    const float* __restrict__ Wr2, const float* __restrict__ br2,
    float* __restrict__ out,
    ushort_t* __restrict__ hbf0, ushort_t* __restrict__ hbf1,
    ushort_t* __restrict__ gjets, float* __restrict__ WiMt,
    ushort_t* __restrict__ WhB, ushort_t* __restrict__ Wr1T,
    float* __restrict__ s_part, float* __restrict__ msg_p,
    float* __restrict__ gmsg_p, float* __restrict__ zsum_p,
    unsigned* __restrict__ bar)
{
  __shared__ __align__(16) short As[64*APITCH];
  __shared__ __align__(16) short Bs[3*64*APITCH];
  __shared__ float redS[256], eS[256], hbS[256];
  __shared__ float gm_s[192], bh_s[192];
  __shared__ float mch[32];

  int t = threadIdx.x, blk = blockIdx.x;
  int lane = t & 63, w = t >> 6;
  int baridx = 0;

  // ================= Phase PE: weight prep + embed =================
  {
    int gid = blk*NT + t, gstride = NBLK*NT;
    for (int e=gid; e<256*768; e+=gstride){ int k=e/768, row=e-k*768; WiMt[e]=Wi[(size_t)row*264 + k]; }
    for (int e=gid; e<768*256; e+=gstride){ WhB[e]=f2bf(Wh[e]); }
    for (int e=gid; e<256*256; e+=gstride){ int n=e>>8, k=e&255; Wr1T[e]=f2bf(Wr1[(size_t)k*256+n]); }
    #pragma unroll
    for (int v=0; v<4; ++v){
      int m = blk*16 + w*4 + v;
      float jr[8];
      #pragma unroll
      for (int f=0; f<8; ++f) jr[f] = jets[m*8+f];
      float sp = 0.f;
      #pragma unroll
      for (int u=0; u<4; ++u){
        int c = lane + 64*u;
        float a = b_emb[c];
        #pragma unroll
        for (int f=0; f<8; ++f) a = fmaf(jr[f], W_emb[f*256+c], a);
        float hv = tanhf(a);
        hbf0[(size_t)m*256 + c] = f2bf(hv);
        sp = fmaf(hv, w_edge[c], sp);
      }
      sp += __shfl_xor(sp,1); sp += __shfl_xor(sp,2); sp += __shfl_xor(sp,4);
      sp += __shfl_xor(sp,8); sp += __shfl_xor(sp,16); sp += __shfl_xor(sp,32);
      if (lane==0) s_part[m] = sp;
      else if (lane<8) s_part[lane*8192 + m] = 0.f;
      #pragma unroll
      for (int g=0; g<3; ++g){
        #pragma unroll
        for (int u=0; u<4; ++u){
          int c = lane + 64*u;
          int rowi = g*256 + c;
          float acc = bi[rowi];
          #pragma unroll
          for (int f=0; f<8; ++f) acc = fmaf(jr[f], Wi[(size_t)rowi*264 + 256 + f], acc);
          gjets[(size_t)m*768 + rowi] = f2bf(acc);
        }
      }
    }
  }
  gbar(bar, baridx++, t);

  ushort_t* hcur = hbf0;
  ushort_t* hnxt = hbf1;
  for (int it=0; it<3; ++it){
    // ===== Phase HM: softmax + hbar-partial + msg-partial (256 units) =====
    if (blk < 256){
      int b = blk >> 3, js = blk & 7, jc = js << 5;
      float s_t = 0.f;
      #pragma unroll
      for (int sl=0; sl<8; ++sl) s_t += s_part[sl*8192 + b*256 + t];
      redS[t] = s_t; __syncthreads();
      for (int o=128;o>0;o>>=1){ if (t<o) redS[t]=fmaxf(redS[t],redS[t+o]); __syncthreads(); }
      float mx = redS[0]; __syncthreads();
      float e = __expf(s_t-mx); eS[t]=e; redS[t]=e; __syncthreads();
      for (int o=128;o>0;o>>=1){ if (t<o) redS[t]+=redS[t+o]; __syncthreads(); }
      float rZ = 1.0f/redS[0];
      const ushort_t* hb = hcur + (size_t)b*256*256;
      float p = 0.f;
      #pragma unroll
      for (int j=0;j<32;++j)
        p = fmaf(eS[jc+j], bf2f(hb[(size_t)(jc+j)*256 + t]), p);
      hbS[t] = p*rZ;
      __syncthreads();
      // msg partial for this j-chunk: (hbar_part) @ W_msg  (linearity)
      float mcol = 0.f;
      #pragma unroll 8
      for (int k=0;k<256;++k)
        mcol = fmaf(hbS[k], W_msg[(size_t)k*256 + t], mcol);
      msg_p[js*8192 + b*256 + t] = mcol;
    }
    gbar(bar, baridx++, t);

    // ===== Phase G: mv=tanh(sum+bias) k-slice, gmsg partials (256 units) =====
    if (blk < 256){
      int b = blk >> 3, ks = blk & 7;
      if (t < 32){
        float v = b_msg[ks*32 + t];
        #pragma unroll
        for (int sl=0; sl<8; ++sl) v += msg_p[sl*8192 + b*256 + ks*32 + t];
        mch[t] = tanhf(v);
      }
      __syncthreads();
      float a0=0.f, a1=0.f, a2=0.f;
      #pragma unroll
      for (int k=0; k<32; ++k){
        float m = mch[k];
        const float* wr_ = &WiMt[(size_t)(ks*32+k)*768 + t];
        a0 = fmaf(m, wr_[0],   a0);
        a1 = fmaf(m, wr_[256], a1);
        a2 = fmaf(m, wr_[512], a2);
      }
      float* gp = &gmsg_p[(size_t)ks*24576 + (size_t)b*768 + t];
      gp[0] = a0; gp[256] = a1; gp[512] = a2;
    }
    gbar(bar, baridx++, t);

    // ===== Phase GRU: MFMA + fused epilogue (512 units, 1/block) =====
    {
      int hcb = blk & 3, mblk = blk >> 2;
      int m0 = mblk*64, hc0 = hcb*64, b = m0 >> 8;
      if (t < 192){
        int g = t>>6, c = t&63;
        int rowi = g*256 + hc0 + c;
        float acc = 0.f;
        #pragma unroll
        for (int sl=0; sl<8; ++sl) acc += gmsg_p[(size_t)sl*24576 + (size_t)b*768 + rowi];
        gm_s[t] = acc;
        bh_s[t] = bh[rowi];
      }
      int wr = w >> 1, wc = w & 1;
      int q = lane >> 4, r = lane & 15;
      int srow = t >> 2, sseg = t & 3;
      f32x4 acc[3][2][2] = {};
      for (int kt = 0; kt < 8; ++kt){
        __syncthreads();
        *(uint4*)&As[srow*APITCH + sseg*8] = *(const uint4*)&hcur[(size_t)(m0+srow)*256 + kt*32 + sseg*8];
        #pragma unroll
        for (int g = 0; g < 3; ++g)
          *(uint4*)&Bs[g*64*APITCH + srow*APITCH + sseg*8] = *(const uint4*)&WhB[(size_t)(g*256 + hc0 + srow)*256 + kt*32 + sseg*8];
        __syncthreads();
        short8 af[2], bfr[3][2];
        #pragma unroll
        for (int fm=0; fm<2; ++fm)
          af[fm] = *(const short8*)&As[(wr*32 + fm*16 + r)*APITCH + q*8];
        #pragma unroll
        for (int g=0; g<3; ++g)
          #pragma unroll
          for (int fn=0; fn<2; ++fn)
            bfr[g][fn] = *(const short8*)&Bs[g*64*APITCH + (wc*32 + fn*16 + r)*APITCH + q*8];
        #pragma unroll
        for (int g=0; g<3; ++g)
          #pragma unroll
          for (int fm=0; fm<2; ++fm)
            #pragma unroll
            for (int fn=0; fn<2; ++fn)
              acc[g][fm][fn] = __builtin_amdgcn_mfma_f32_16x16x32_bf16(af[fm], bfr[g][fn], acc[g][fm][fn], 0,0,0);
      }
      float wef[2];
      wef[0] = w_edge[hc0 + wc*32 + r];
      wef[1] = w_edge[hc0 + wc*32 + 16 + r];
      float pacc[2][4] = {};
      #pragma unroll
      for (int fm=0; fm<2; ++fm)
        #pragma unroll
        for (int fn=0; fn<2; ++fn){
          int cloc = wc*32 + fn*16 + r;
          int hcol = hc0 + cloc;
          #pragma unroll
          for (int jj=0; jj<4; ++jj){
            int m = m0 + wr*32 + fm*16 + q*4 + jj;
            float gir = bf2f(gjets[(size_t)m*768 + hcol])       + gm_s[cloc];
            float giz = bf2f(gjets[(size_t)m*768 + 256 + hcol]) + gm_s[64+cloc];
            float gin = bf2f(gjets[(size_t)m*768 + 512 + hcol]) + gm_s[128+cloc];
            float rr = sigmoidf_(gir + acc[0][fm][fn][jj] + bh_s[cloc]);
            float zz = sigmoidf_(giz + acc[1][fm][fn][jj] + bh_s[64+cloc]);
            float nn = tanhf(gin + rr*(acc[2][fm][fn][jj] + bh_s[128+cloc]));
            float ho = bf2f(hcur[(size_t)m*256 + hcol]);
            float hn = (1.f - zz)*nn + zz*ho;
            hnxt[(size_t)m*256 + hcol] = f2bf(hn);
            pacc[fm][jj] = fmaf(wef[fn], hn, pacc[fm][jj]);
          }
        }
      if (it < 2){
        #pragma unroll
        for (int fm=0; fm<2; ++fm)
          #pragma unroll
          for (int jj=0; jj<4; ++jj){
            float p = pacc[fm][jj];
            p += __shfl_xor(p,1); p += __shfl_xor(p,2);
            p += __shfl_xor(p,4); p += __shfl_xor(p,8);
            if (r == 0)
              s_part[(hcb*2 + wc)*8192 + m0 + wr*32 + fm*16 + q*4 + jj] = p;
          }
      }
    }
    gbar(bar, baridx++, t);
    ushort_t* tmp = hcur; hcur = hnxt; hnxt = tmp;
  }

  // ===== Phase RO: readout MFMA (512 units, 1/block) =====
  {
    int ncb = blk & 3, mblk = blk >> 2;
    int m0 = mblk*64, nc0 = ncb*64, b = m0 >> 8;
    int wr = w >> 1, wc = w & 1;
    int q = lane >> 4, r = lane & 15;
    int srow = t >> 2, sseg = t & 3;
    f32x4 acc[2][2] = {};
    for (int kt = 0; kt < 8; ++kt){
      __syncthreads();
      *(uint4*)&As[srow*APITCH + sseg*8] = *(const uint4*)&hcur[(size_t)(m0+srow)*256 + kt*32 + sseg*8];
      *(uint4*)&Bs[srow*APITCH + sseg*8] = *(const uint4*)&Wr1T[(size_t)(nc0+srow)*256 + kt*32 + sseg*8];
      __syncthreads();
      short8 af[2], bfr[2];
      #pragma unroll
      for (int fm=0; fm<2; ++fm)
        af[fm] = *(const short8*)&As[(wr*32 + fm*16 + r)*APITCH + q*8];
      #pragma unroll
      for (int fn=0; fn<2; ++fn)
        bfr[fn] = *(const short8*)&Bs[(wc*32 + fn*16 + r)*APITCH + q*8];
      #pragma unroll
      for (int fm=0; fm<2; ++fm)
        #pragma unroll
        for (int fn=0; fn<2; ++fn)
          acc[fm][fn] = __builtin_amdgcn_mfma_f32_16x16x32_bf16(af[fm], bfr[fn], acc[fm][fn], 0,0,0);
    }
    #pragma unroll
    for (int fn=0; fn<2; ++fn){
      int n = nc0 + wc*32 + fn*16 + r;
      float bb = br1[n];
      float cs = 0.f;
      #pragma unroll
      for (int fm=0; fm<2; ++fm)
        #pragma unroll
        for (int jj=0; jj<4; ++jj)
          cs += fmaxf(acc[fm][fn][jj] + bb, 0.f);
      cs += __shfl_xor(cs, 16);
      cs += __shfl_xor(cs, 32);
      int wr2_ = (t >> 6) >> 1;
      if (q == 0) zsum_p[((mblk&3)*2 + wr2_)*8192 + b*256 + n] = cs;
    }
  }
  gbar(bar, baridx++, t);

  // ===== Phase FIN: out = (Σ zsum slots) @ Wr2 + 256*br2 (32 blocks) =====
  if (blk < 32){
    int b = blk;
    float z = 0.f;
    #pragma unroll
    for (int sl=0; sl<8; ++sl) z += zsum_p[sl*8192 + b*256 + t];
    eS[t] = z; __syncthreads();
    float acc = 0.f;
    #pragma unroll 8
    for (int k=0;k<256;++k) acc = fmaf(eS[k], Wr2[(size_t)k*256 + t], acc);
    out[b*256 + t] = acc + 256.0f*br2[t];
  }
}

extern "C" void kernel_launch(void* const* d_in, const int* in_sizes, int n_in,
                              void* d_out, int out_size, void* d_ws, size_t ws_size,
                              hipStream_t stream){
  (void)in_sizes; (void)n_in; (void)out_size; (void)ws_size;
  const float* jets  = (const float*)d_in[0];
  const float* W_emb = (const float*)d_in[1];
  const float* b_emb = (const float*)d_in[2];
  const float* w_edge= (const float*)d_in[3];
  // d_in[4] = b_edge: cancels in softmax
  const float* W_msg = (const float*)d_in[5];
  const float* b_msg = (const float*)d_in[6];
  const float* Wi    = (const float*)d_in[7];
  const float* bi    = (const float*)d_in[8];
  const float* Wh    = (const float*)d_in[9];
  const float* bh    = (const float*)d_in[10];
  const float* Wr1   = (const float*)d_in[11];
  const float* br1   = (const float*)d_in[12];
  const float* Wr2   = (const float*)d_in[13];
  const float* br2   = (const float*)d_in[14];
  float* out = (float*)d_out;
  float* ws  = (float*)d_ws;
  // workspace layout (float-slot units)
  ushort_t* hbf0  = (ushort_t*)ws;                  // 1,048,576 f
  ushort_t* hbf1  = (ushort_t*)(ws + 1048576);      // 1,048,576 f
  ushort_t* gjets = (ushort_t*)(ws + 2097152);      // 3,145,728 f
  float* WiMt     = ws + 5242880;                   // 196,608 (f32 [k=256][row=768])
  ushort_t* WhB   = (ushort_t*)(ws + 5439488);      // 98,304 f
  ushort_t* Wr1T  = (ushort_t*)(ws + 5537792);      // 32,768 f
  float* s_part   = ws + 5570560;                   // [8][8192]
  float* msg_p    = ws + 5636096;                   // [8][8192]
  float* gmsg_p   = ws + 5701632;                   // [8][24576]
  float* zsum_p   = ws + 5898240;                   // [8][8192]
  unsigned* bar   = (unsigned*)(ws + 5963776);      // 32 u32 (end ~23.9MB)

  hipMemsetAsync(bar, 0, 32*sizeof(unsigned), stream);
  k_mega<<<NBLK, NT, 0, stream>>>(jets, W_emb, b_emb, w_edge, W_msg, b_msg,
                                  Wi, bi, Wh, bh, Wr1, br1, Wr2, br2, out,
                                  hbf0, hbf1, gjets, WiMt, WhB, Wr1T,
                                  s_part, msg_p, gmsg_p, zsum_p, bar);
}

// Round 12
// 163.950 us; speedup vs baseline: 17.0074x; 17.0074x over previous
//
#include <hip/hip_runtime.h>
#include <math.h>

#define NT 256
#define APITCH 40

typedef __attribute__((ext_vector_type(8))) short short8;
typedef __attribute__((ext_vector_type(4))) float f32x4;
typedef unsigned short ushort_t;

__device__ __forceinline__ float sigmoidf_(float x){ return 1.0f/(1.0f+__expf(-x)); }
__device__ __forceinline__ ushort_t f2bf(float x){
  unsigned int u = __float_as_uint(x);
  u = u + 0x7fff + ((u>>16)&1);
  return (ushort_t)(u>>16);
}
__device__ __forceinline__ float bf2f(ushort_t b){
  return __uint_as_float(((unsigned int)b)<<16);
}

// ---- PE: weight prep (grid-stride) + embed (16 rows/block). 512 blocks. ----
__global__ __launch_bounds__(256) void k_pe(
    const float* __restrict__ jets, const float* __restrict__ W_emb,
    const float* __restrict__ b_emb, const float* __restrict__ w_edge,
    const float* __restrict__ Wi, const float* __restrict__ bi,
    const float* __restrict__ Wh, const float* __restrict__ Wr1,
    ushort_t* __restrict__ hbf0, ushort_t* __restrict__ gjets,
    ushort_t* __restrict__ WhB, ushort_t* __restrict__ Wr1T,
    float* __restrict__ s_part)
{
  int t = threadIdx.x, blk = blockIdx.x;
  int gid = blk*NT + t, gstride = gridDim.x*NT;
  for (int e=gid; e<768*256; e+=gstride){ WhB[e]=f2bf(Wh[e]); }
  for (int e=gid; e<256*256; e+=gstride){ int n=e>>8, k=e&255; Wr1T[e]=f2bf(Wr1[(size_t)k*256+n]); }
  int lane = t & 63, w = t >> 6;
  #pragma unroll
  for (int v=0; v<4; ++v){
    int m = blk*16 + w*4 + v;
    float jr[8];
    #pragma unroll
    for (int f=0; f<8; ++f) jr[f] = jets[m*8+f];
    float sp = 0.f;
    #pragma unroll
    for (int u=0; u<4; ++u){
      int c = lane + 64*u;
      float a = b_emb[c];
      #pragma unroll
      for (int f=0; f<8; ++f) a = fmaf(jr[f], W_emb[f*256+c], a);
      float hv = tanhf(a);
      hbf0[(size_t)m*256 + c] = f2bf(hv);
      sp = fmaf(hv, w_edge[c], sp);
    }
    sp += __shfl_xor(sp,1); sp += __shfl_xor(sp,2); sp += __shfl_xor(sp,4);
    sp += __shfl_xor(sp,8); sp += __shfl_xor(sp,16); sp += __shfl_xor(sp,32);
    if (lane==0) s_part[m] = sp;
    else if (lane<8) s_part[lane*8192 + m] = 0.f;
    #pragma unroll
    for (int g=0; g<3; ++g){
      #pragma unroll
      for (int u=0; u<4; ++u){
        int c = lane + 64*u;
        int rowi = g*256 + c;
        float acc = bi[rowi];
        #pragma unroll
        for (int f=0; f<8; ++f) acc = fmaf(jr[f], Wi[(size_t)rowi*264 + 256 + f], acc);
        gjets[(size_t)m*768 + rowi] = f2bf(acc);
      }
    }
  }
}

// ---- HM: softmax + hbar j-chunk partial + msg partial (linearity).
//      256 blocks = (batch, j-chunk); writes msg_p slot js. ----
__global__ __launch_bounds__(256) void k_hm(const ushort_t* __restrict__ hbf,
    const float* __restrict__ s_part, const float* __restrict__ W_msg,
    float* __restrict__ msg_p){
  int t = threadIdx.x;
  int b = blockIdx.x >> 3, js = blockIdx.x & 7;
  int jc = js << 5;
  __shared__ float eS[256], red[256], hbS[256];
  float s_t = 0.f;
  #pragma unroll
  for (int sl=0; sl<8; ++sl) s_t += s_part[sl*8192 + b*256 + t];
  red[t] = s_t; __syncthreads();
  for (int o=128;o>0;o>>=1){ if (t<o) red[t]=fmaxf(red[t],red[t+o]); __syncthreads(); }
  float mx = red[0]; __syncthreads();
  float e = __expf(s_t-mx); eS[t]=e; red[t]=e; __syncthreads();
  for (int o=128;o>0;o>>=1){ if (t<o) red[t]+=red[t+o]; __syncthreads(); }
  float rZ = 1.0f/red[0];
  const ushort_t* hb = hbf + (size_t)b*256*256;
  float p = 0.f;
  #pragma unroll
  for (int j=0;j<32;++j)
    p = fmaf(eS[jc+j], bf2f(hb[(size_t)(jc+j)*256 + t]), p);
  hbS[t] = p*rZ;
  __syncthreads();
  float mcol = 0.f;
  #pragma unroll 8
  for (int k=0;k<256;++k)
    mcol = fmaf(hbS[k], W_msg[(size_t)k*256 + t], mcol);
  msg_p[js*8192 + b*256 + t] = mcol;
}

// ---- GRU: prologue computes mv + gmsg strip from Wi directly (float4 rows),
//      then MFMA gh = h@Wh.T + fused GRU epilogue + s_part slot writes. 512 blocks ----
__global__ __launch_bounds__(256) void k_gru_mfma(
    const ushort_t* __restrict__ hbf_in,
    const ushort_t* __restrict__ WhB, const float* __restrict__ bh,
    const ushort_t* __restrict__ gjets, const float* __restrict__ msg_p,
    const float* __restrict__ b_msg, const float* __restrict__ Wi,
    const float* __restrict__ w_edge,
    ushort_t* __restrict__ hbf_out, float* __restrict__ s_part, int compute_s)
{
  __shared__ __align__(16) short As[64*APITCH];
  __shared__ __align__(16) short Bs[3*64*APITCH];
  __shared__ float mvS[256];
  __shared__ float gm_s[192], bh_s[192];
  int t = threadIdx.x;
  int hcb = blockIdx.x & 3, mblk = blockIdx.x >> 2;
  int m0 = mblk*64, hc0 = hcb*64, b = m0 >> 8;
  // mv = tanh(b_msg + sum of msg_p slots)
  {
    float v = b_msg[t];
    #pragma unroll
    for (int sl=0; sl<8; ++sl) v += msg_p[sl*8192 + b*256 + t];
    mvS[t] = tanhf(v);
  }
  __syncthreads();
  // gmsg strip: gm_s[rowi] = mv . Wi[rowi, 0:256]  (row-contiguous float4 reads)
  if (t < 192){
    int g = t>>6, c = t&63;
    int rowi = g*256 + hc0 + c;
    const float4* wrow = (const float4*)&Wi[(size_t)rowi*264];
    float acc = 0.f;
    #pragma unroll 8
    for (int k4=0; k4<64; ++k4){
      float4 wv = wrow[k4];
      acc = fmaf(mvS[k4*4],   wv.x, acc);
      acc = fmaf(mvS[k4*4+1], wv.y, acc);
      acc = fmaf(mvS[k4*4+2], wv.z, acc);
      acc = fmaf(mvS[k4*4+3], wv.w, acc);
    }
    gm_s[t] = acc;
    bh_s[t] = bh[rowi];
  }
  int lane = t & 63, w = t >> 6;
  int wr = w >> 1, wc = w & 1;
  int q = lane >> 4, r = lane & 15;
  int srow = t >> 2, sseg = t & 3;
  f32x4 acc[3][2][2] = {};
  for (int kt = 0; kt < 8; ++kt){
    __syncthreads();
    *(uint4*)&As[srow*APITCH + sseg*8] = *(const uint4*)&hbf_in[(size_t)(m0+srow)*256 + kt*32 + sseg*8];
    #pragma unroll
    for (int g = 0; g < 3; ++g)
      *(uint4*)&Bs[g*64*APITCH + srow*APITCH + sseg*8] = *(const uint4*)&WhB[(size_t)(g*256 + hc0 + srow)*256 + kt*32 + sseg*8];
    __syncthreads();
    short8 af[2], bfr[3][2];
    #pragma unroll
    for (int fm=0; fm<2; ++fm)
      af[fm] = *(const short8*)&As[(wr*32 + fm*16 + r)*APITCH + q*8];
    #pragma unroll
    for (int g=0; g<3; ++g)
      #pragma unroll
      for (int fn=0; fn<2; ++fn)
        bfr[g][fn] = *(const short8*)&Bs[g*64*APITCH + (wc*32 + fn*16 + r)*APITCH + q*8];
    #pragma unroll
    for (int g=0; g<3; ++g)
      #pragma unroll
      for (int fm=0; fm<2; ++fm)
        #pragma unroll
        for (int fn=0; fn<2; ++fn)
          acc[g][fm][fn] = __builtin_amdgcn_mfma_f32_16x16x32_bf16(af[fm], bfr[g][fn], acc[g][fm][fn], 0,0,0);
  }
  float wef[2];
  wef[0] = w_edge[hc0 + wc*32 + r];
  wef[1] = w_edge[hc0 + wc*32 + 16 + r];
  float pacc[2][4] = {};
  #pragma unroll
  for (int fm=0; fm<2; ++fm)
    #pragma unroll
    for (int fn=0; fn<2; ++fn){
      int cloc = wc*32 + fn*16 + r;
      int hcol = hc0 + cloc;
      #pragma unroll
      for (int jj=0; jj<4; ++jj){
        int m = m0 + wr*32 + fm*16 + q*4 + jj;
        float gir = bf2f(gjets[(size_t)m*768 + hcol])       + gm_s[cloc];
        float giz = bf2f(gjets[(size_t)m*768 + 256 + hcol]) + gm_s[64+cloc];
        float gin = bf2f(gjets[(size_t)m*768 + 512 + hcol]) + gm_s[128+cloc];
        float rr = sigmoidf_(gir + acc[0][fm][fn][jj] + bh_s[cloc]);
        float zz = sigmoidf_(giz + acc[1][fm][fn][jj] + bh_s[64+cloc]);
        float nn = tanhf(gin + rr*(acc[2][fm][fn][jj] + bh_s[128+cloc]));
        float ho = bf2f(hbf_in[(size_t)m*256 + hcol]);
        float hn = (1.f - zz)*nn + zz*ho;
        hbf_out[(size_t)m*256 + hcol] = f2bf(hn);
        pacc[fm][jj] = fmaf(wef[fn], hn, pacc[fm][jj]);
      }
    }
  if (compute_s){
    #pragma unroll
    for (int fm=0; fm<2; ++fm)
      #pragma unroll
      for (int jj=0; jj<4; ++jj){
        float p = pacc[fm][jj];
        p += __shfl_xor(p,1); p += __shfl_xor(p,2);
        p += __shfl_xor(p,4); p += __shfl_xor(p,8);
        if (r == 0)
          s_part[(hcb*2 + wc)*8192 + m0 + wr*32 + fm*16 + q*4 + jj] = p;
      }
  }
}

// ---- readout MFMA: slot partial writes. 512 blocks ----
__global__ __launch_bounds__(256) void k_ro(
    const ushort_t* __restrict__ hbf, const ushort_t* __restrict__ Wr1T,
    const float* __restrict__ br1, float* __restrict__ zsum_p)
{
  __shared__ __align__(16) short As[64*APITCH];
  __shared__ __align__(16) short Bs[64*APITCH];
  int t = threadIdx.x;
  int ncb = blockIdx.x & 3, mblk = blockIdx.x >> 2;
  int m0 = mblk*64, nc0 = ncb*64, b = m0 >> 8;
  int lane = t & 63, w = t >> 6;
  int wr = w >> 1, wc = w & 1;
  int q = lane >> 4, r = lane & 15;
  int srow = t >> 2, sseg = t & 3;
  f32x4 acc[2][2] = {};
  for (int kt = 0; kt < 8; ++kt){
    __syncthreads();
    *(uint4*)&As[srow*APITCH + sseg*8] = *(const uint4*)&hbf[(size_t)(m0+srow)*256 + kt*32 + sseg*8];
    *(uint4*)&Bs[srow*APITCH + sseg*8] = *(const uint4*)&Wr1T[(size_t)(nc0+srow)*256 + kt*32 + sseg*8];
    __syncthreads();
    short8 af[2], bfr[2];
    #pragma unroll
    for (int fm=0; fm<2; ++fm)
      af[fm] = *(const short8*)&As[(wr*32 + fm*16 + r)*APITCH + q*8];
    #pragma unroll
    for (int fn=0; fn<2; ++fn)
      bfr[fn] = *(const short8*)&Bs[(wc*32 + fn*16 + r)*APITCH + q*8];
    #pragma unroll
    for (int fm=0; fm<2; ++fm)
      #pragma unroll
      for (int fn=0; fn<2; ++fn)
        acc[fm][fn] = __builtin_amdgcn_mfma_f32_16x16x32_bf16(af[fm], bfr[fn], acc[fm][fn], 0,0,0);
  }
  #pragma unroll
  for (int fn=0; fn<2; ++fn){
    int n = nc0 + wc*32 + fn*16 + r;
    float bb = br1[n];
    float cs = 0.f;
    #pragma unroll
    for (int fm=0; fm<2; ++fm)
      #pragma unroll
      for (int jj=0; jj<4; ++jj)
        cs += fmaxf(acc[fm][fn][jj] + bb, 0.f);
    cs += __shfl_xor(cs, 16);
    cs += __shfl_xor(cs, 32);
    if (q == 0) zsum_p[((mblk&3)*2 + wr)*8192 + b*256 + n] = cs;
  }
}

// ---- final: out[b,:] = (Σ slots zsum)[b,:] @ Wr2 + N*br2. 32 blocks ----
__global__ __launch_bounds__(256) void k_fin(const float* __restrict__ zsum_p,
    const float* __restrict__ Wr2, const float* __restrict__ br2,
    float* __restrict__ out){
  int b = blockIdx.x, t = threadIdx.x;
  __shared__ float zs[256];
  float z = 0.f;
  #pragma unroll
  for (int sl=0; sl<8; ++sl) z += zsum_p[sl*8192 + b*256 + t];
  zs[t] = z; __syncthreads();
  float acc = 0.f;
  #pragma unroll 8
  for (int k=0;k<256;++k) acc = fmaf(zs[k], Wr2[(size_t)k*256 + t], acc);
  out[b*256 + t] = acc + 256.0f*br2[t];
}

extern "C" void kernel_launch(void* const* d_in, const int* in_sizes, int n_in,
                              void* d_out, int out_size, void* d_ws, size_t ws_size,
                              hipStream_t stream){
  (void)in_sizes; (void)n_in; (void)out_size; (void)ws_size;
  const float* jets  = (const float*)d_in[0];
  const float* W_emb = (const float*)d_in[1];
  const float* b_emb = (const float*)d_in[2];
  const float* w_edge= (const float*)d_in[3];
  // d_in[4] = b_edge: cancels in softmax
  const float* W_msg = (const float*)d_in[5];
  const float* b_msg = (const float*)d_in[6];
  const float* Wi    = (const float*)d_in[7];
  const float* bi    = (const float*)d_in[8];
  const float* Wh    = (const float*)d_in[9];
  const float* bh    = (const float*)d_in[10];
  const float* Wr1   = (const float*)d_in[11];
  const float* br1   = (const float*)d_in[12];
  const float* Wr2   = (const float*)d_in[13];
  const float* br2   = (const float*)d_in[14];
  float* out = (float*)d_out;
  float* ws  = (float*)d_ws;
  // workspace layout (float-slot units)
  ushort_t* hbf0  = (ushort_t*)ws;                  // 1,048,576 f
  ushort_t* hbf1  = (ushort_t*)(ws + 1048576);      // 1,048,576 f
  ushort_t* gjets = (ushort_t*)(ws + 2097152);      // 3,145,728 f
  ushort_t* WhB   = (ushort_t*)(ws + 5242880);      // 98,304 f
  ushort_t* Wr1T  = (ushort_t*)(ws + 5341184);      // 32,768 f
  float* s_part   = ws + 5373952;                   // [8][8192]
  float* msg_p    = ws + 5439488;                   // [8][8192]
  float* zsum_p   = ws + 5505024;                   // [8][8192] (end 5,570,560 f = 22.3MB)
  ushort_t* hbf[2] = {hbf0, hbf1};

  k_pe<<<512,NT,0,stream>>>(jets, W_emb, b_emb, w_edge, Wi, bi, Wh, Wr1,
                            hbf[0], gjets, WhB, Wr1T, s_part);
  for (int it=0; it<3; ++it){
    int cur = it & 1, nxt = cur ^ 1;
    k_hm<<<256,NT,0,stream>>>(hbf[cur], s_part, W_msg, msg_p);
    k_gru_mfma<<<512,NT,0,stream>>>(hbf[cur], WhB, bh, gjets, msg_p, b_msg,
                                    Wi, w_edge, hbf[nxt], s_part, (it<2)?1:0);
  }
  k_ro<<<512,NT,0,stream>>>(hbf[1], Wr1T, br1, zsum_p);
  k_fin<<<32,NT,0,stream>>>(zsum_p, Wr2, br2, out);
}

// Round 13
// 153.177 us; speedup vs baseline: 18.2034x; 1.0703x over previous
//
#include <hip/hip_runtime.h>
#include <math.h>

#define NT 256
#define APITCH 40

typedef __attribute__((ext_vector_type(8))) short short8;
typedef __attribute__((ext_vector_type(4))) float f32x4;
typedef unsigned short ushort_t;

__device__ __forceinline__ float sigmoidf_(float x){ return 1.0f/(1.0f+__expf(-x)); }
__device__ __forceinline__ ushort_t f2bf(float x){
  unsigned int u = __float_as_uint(x);
  u = u + 0x7fff + ((u>>16)&1);
  return (ushort_t)(u>>16);
}
__device__ __forceinline__ float bf2f(ushort_t b){
  return __uint_as_float(((unsigned int)b)<<16);
}

// ---- PE: weight prep (grid-stride) + embed (16 rows/block). 512 blocks. ----
__global__ __launch_bounds__(256) void k_pe(
    const float* __restrict__ jets, const float* __restrict__ W_emb,
    const float* __restrict__ b_emb, const float* __restrict__ w_edge,
    const float* __restrict__ Wi, const float* __restrict__ bi,
    const float* __restrict__ Wh, const float* __restrict__ Wr1,
    ushort_t* __restrict__ hbf0, ushort_t* __restrict__ gjets,
    float* __restrict__ WiMt, ushort_t* __restrict__ WhB,
    ushort_t* __restrict__ Wr1T, float* __restrict__ s_part)
{
  int t = threadIdx.x, blk = blockIdx.x;
  int gid = blk*NT + t, gstride = gridDim.x*NT;
  for (int e=gid; e<256*768; e+=gstride){ int k=e/768, row=e-k*768; WiMt[e]=Wi[(size_t)row*264 + k]; }
  for (int e=gid; e<768*256; e+=gstride){ WhB[e]=f2bf(Wh[e]); }
  for (int e=gid; e<256*256; e+=gstride){ int n=e>>8, k=e&255; Wr1T[e]=f2bf(Wr1[(size_t)k*256+n]); }
  int lane = t & 63, w = t >> 6;
  #pragma unroll
  for (int v=0; v<4; ++v){
    int m = blk*16 + w*4 + v;
    float jr[8];
    #pragma unroll
    for (int f=0; f<8; ++f) jr[f] = jets[m*8+f];
    float sp = 0.f;
    #pragma unroll
    for (int u=0; u<4; ++u){
      int c = lane + 64*u;
      float a = b_emb[c];
      #pragma unroll
      for (int f=0; f<8; ++f) a = fmaf(jr[f], W_emb[f*256+c], a);
      float hv = tanhf(a);
      hbf0[(size_t)m*256 + c] = f2bf(hv);
      sp = fmaf(hv, w_edge[c], sp);
    }
    sp += __shfl_xor(sp,1); sp += __shfl_xor(sp,2); sp += __shfl_xor(sp,4);
    sp += __shfl_xor(sp,8); sp += __shfl_xor(sp,16); sp += __shfl_xor(sp,32);
    if (lane==0) s_part[m] = sp;
    else if (lane<8) s_part[lane*8192 + m] = 0.f;
    #pragma unroll
    for (int g=0; g<3; ++g){
      #pragma unroll
      for (int u=0; u<4; ++u){
        int c = lane + 64*u;
        int rowi = g*256 + c;
        float acc = bi[rowi];
        #pragma unroll
        for (int f=0; f<8; ++f) acc = fmaf(jr[f], Wi[(size_t)rowi*264 + 256 + f], acc);
        gjets[(size_t)m*768 + rowi] = f2bf(acc);
      }
    }
  }
}

// ---- HM: softmax + hbar j-chunk partial + msg partial (linearity).
//      256 blocks = (batch, j-chunk); writes msg_p slot js. ----
__global__ __launch_bounds__(256) void k_hm(const ushort_t* __restrict__ hbf,
    const float* __restrict__ s_part, const float* __restrict__ W_msg,
    float* __restrict__ msg_p){
  int t = threadIdx.x;
  int b = blockIdx.x >> 3, js = blockIdx.x & 7;
  int jc = js << 5;
  __shared__ float eS[256], red[256], hbS[256];
  float s_t = 0.f;
  #pragma unroll
  for (int sl=0; sl<8; ++sl) s_t += s_part[sl*8192 + b*256 + t];
  red[t] = s_t; __syncthreads();
  for (int o=128;o>0;o>>=1){ if (t<o) red[t]=fmaxf(red[t],red[t+o]); __syncthreads(); }
  float mx = red[0]; __syncthreads();
  float e = __expf(s_t-mx); eS[t]=e; red[t]=e; __syncthreads();
  for (int o=128;o>0;o>>=1){ if (t<o) red[t]+=red[t+o]; __syncthreads(); }
  float rZ = 1.0f/red[0];
  const ushort_t* hb = hbf + (size_t)b*256*256;
  float p = 0.f;
  #pragma unroll
  for (int j=0;j<32;++j)
    p = fmaf(eS[jc+j], bf2f(hb[(size_t)(jc+j)*256 + t]), p);
  hbS[t] = p*rZ;
  __syncthreads();
  float mcol = 0.f;
  #pragma unroll 8
  for (int k=0;k<256;++k)
    mcol = fmaf(hbS[k], W_msg[(size_t)k*256 + t], mcol);
  msg_p[js*8192 + b*256 + t] = mcol;
}

// ---- gmsg partials: 256 blocks = (batch, k-slice). mv=tanh(sum+bias) local ----
__global__ __launch_bounds__(256) void k_gmsgp(const float* __restrict__ msg_p,
    const float* __restrict__ b_msg, const float* __restrict__ WiMt,
    float* __restrict__ gmsg_p){
  int t = threadIdx.x;
  int b = blockIdx.x >> 3, ks = blockIdx.x & 7;
  __shared__ float mch[32];
  if (t < 32){
    float v = b_msg[ks*32 + t];
    #pragma unroll
    for (int sl=0; sl<8; ++sl) v += msg_p[sl*8192 + b*256 + ks*32 + t];
    mch[t] = tanhf(v);
  }
  __syncthreads();
  float a0=0.f, a1=0.f, a2=0.f;
  #pragma unroll
  for (int k=0; k<32; ++k){
    float m = mch[k];
    const float* wr = &WiMt[(size_t)(ks*32+k)*768 + t];
    a0 = fmaf(m, wr[0],   a0);
    a1 = fmaf(m, wr[256], a1);
    a2 = fmaf(m, wr[512], a2);
  }
  float* gp = &gmsg_p[(size_t)ks*24576 + (size_t)b*768 + t];
  gp[0] = a0; gp[256] = a1; gp[512] = a2;
}

// ---- GRU via MFMA + fused epilogue + s_part slot writes. 512 blocks ----
__global__ __launch_bounds__(256) void k_gru_mfma(
    const ushort_t* __restrict__ hbf_in,
    const ushort_t* __restrict__ WhB, const float* __restrict__ bh,
    const ushort_t* __restrict__ gjets, const float* __restrict__ gmsg_p,
    const float* __restrict__ w_edge,
    ushort_t* __restrict__ hbf_out, float* __restrict__ s_part, int compute_s)
{
  __shared__ __align__(16) short As[64*APITCH];
  __shared__ __align__(16) short Bs[3*64*APITCH];
  __shared__ float gm_s[192], bh_s[192];
  int t = threadIdx.x;
  int hcb = blockIdx.x & 3, mblk = blockIdx.x >> 2;
  int m0 = mblk*64, hc0 = hcb*64, b = m0 >> 8;
  if (t < 192){
    int g = t>>6, c = t&63;
    int rowi = g*256 + hc0 + c;
    float acc = 0.f;
    #pragma unroll
    for (int sl=0; sl<8; ++sl) acc += gmsg_p[(size_t)sl*24576 + (size_t)b*768 + rowi];
    gm_s[t] = acc;
    bh_s[t] = bh[rowi];
  }
  int lane = t & 63, w = t >> 6;
  int wr = w >> 1, wc = w & 1;
  int q = lane >> 4, r = lane & 15;
  int srow = t >> 2, sseg = t & 3;
  f32x4 acc[3][2][2] = {};
  for (int kt = 0; kt < 8; ++kt){
    __syncthreads();
    *(uint4*)&As[srow*APITCH + sseg*8] = *(const uint4*)&hbf_in[(size_t)(m0+srow)*256 + kt*32 + sseg*8];
    #pragma unroll
    for (int g = 0; g < 3; ++g)
      *(uint4*)&Bs[g*64*APITCH + srow*APITCH + sseg*8] = *(const uint4*)&WhB[(size_t)(g*256 + hc0 + srow)*256 + kt*32 + sseg*8];
    __syncthreads();
    short8 af[2], bfr[3][2];
    #pragma unroll
    for (int fm=0; fm<2; ++fm)
      af[fm] = *(const short8*)&As[(wr*32 + fm*16 + r)*APITCH + q*8];
    #pragma unroll
    for (int g=0; g<3; ++g)
      #pragma unroll
      for (int fn=0; fn<2; ++fn)
        bfr[g][fn] = *(const short8*)&Bs[g*64*APITCH + (wc*32 + fn*16 + r)*APITCH + q*8];
    #pragma unroll
    for (int g=0; g<3; ++g)
      #pragma unroll
      for (int fm=0; fm<2; ++fm)
        #pragma unroll
        for (int fn=0; fn<2; ++fn)
          acc[g][fm][fn] = __builtin_amdgcn_mfma_f32_16x16x32_bf16(af[fm], bfr[g][fn], acc[g][fm][fn], 0,0,0);
  }
  float wef[2];
  wef[0] = w_edge[hc0 + wc*32 + r];
  wef[1] = w_edge[hc0 + wc*32 + 16 + r];
  float pacc[2][4] = {};
  #pragma unroll
  for (int fm=0; fm<2; ++fm)
    #pragma unroll
    for (int fn=0; fn<2; ++fn){
      int cloc = wc*32 + fn*16 + r;
      int hcol = hc0 + cloc;
      #pragma unroll
      for (int jj=0; jj<4; ++jj){
        int m = m0 + wr*32 + fm*16 + q*4 + jj;
        float gir = bf2f(gjets[(size_t)m*768 + hcol])       + gm_s[cloc];
        float giz = bf2f(gjets[(size_t)m*768 + 256 + hcol]) + gm_s[64+cloc];
        float gin = bf2f(gjets[(size_t)m*768 + 512 + hcol]) + gm_s[128+cloc];
        float rr = sigmoidf_(gir + acc[0][fm][fn][jj] + bh_s[cloc]);
        float zz = sigmoidf_(giz + acc[1][fm][fn][jj] + bh_s[64+cloc]);
        float nn = tanhf(gin + rr*(acc[2][fm][fn][jj] + bh_s[128+cloc]));
        float ho = bf2f(hbf_in[(size_t)m*256 + hcol]);
        float hn = (1.f - zz)*nn + zz*ho;
        hbf_out[(size_t)m*256 + hcol] = f2bf(hn);
        pacc[fm][jj] = fmaf(wef[fn], hn, pacc[fm][jj]);
      }
    }
  if (compute_s){
    #pragma unroll
    for (int fm=0; fm<2; ++fm)
      #pragma unroll
      for (int jj=0; jj<4; ++jj){
        float p = pacc[fm][jj];
        p += __shfl_xor(p,1); p += __shfl_xor(p,2);
        p += __shfl_xor(p,4); p += __shfl_xor(p,8);
        if (r == 0)
          s_part[(hcb*2 + wc)*8192 + m0 + wr*32 + fm*16 + q*4 + jj] = p;
      }
  }
}

// ---- readout MFMA: slot partial writes. 512 blocks ----
__global__ __launch_bounds__(256) void k_ro(
    const ushort_t* __restrict__ hbf, const ushort_t* __restrict__ Wr1T,
    const float* __restrict__ br1, float* __restrict__ zsum_p)
{
  __shared__ __align__(16) short As[64*APITCH];
  __shared__ __align__(16) short Bs[64*APITCH];
  int t = threadIdx.x;
  int ncb = blockIdx.x & 3, mblk = blockIdx.x >> 2;
  int m0 = mblk*64, nc0 = ncb*64, b = m0 >> 8;
  int lane = t & 63, w = t >> 6;
  int wr = w >> 1, wc = w & 1;
  int q = lane >> 4, r = lane & 15;
  int srow = t >> 2, sseg = t & 3;
  f32x4 acc[2][2] = {};
  for (int kt = 0; kt < 8; ++kt){
    __syncthreads();
    *(uint4*)&As[srow*APITCH + sseg*8] = *(const uint4*)&hbf[(size_t)(m0+srow)*256 + kt*32 + sseg*8];
    *(uint4*)&Bs[srow*APITCH + sseg*8] = *(const uint4*)&Wr1T[(size_t)(nc0+srow)*256 + kt*32 + sseg*8];
    __syncthreads();
    short8 af[2], bfr[2];
    #pragma unroll
    for (int fm=0; fm<2; ++fm)
      af[fm] = *(const short8*)&As[(wr*32 + fm*16 + r)*APITCH + q*8];
    #pragma unroll
    for (int fn=0; fn<2; ++fn)
      bfr[fn] = *(const short8*)&Bs[(wc*32 + fn*16 + r)*APITCH + q*8];
    #pragma unroll
    for (int fm=0; fm<2; ++fm)
      #pragma unroll
      for (int fn=0; fn<2; ++fn)
        acc[fm][fn] = __builtin_amdgcn_mfma_f32_16x16x32_bf16(af[fm], bfr[fn], acc[fm][fn], 0,0,0);
  }
  #pragma unroll
  for (int fn=0; fn<2; ++fn){
    int n = nc0 + wc*32 + fn*16 + r;
    float bb = br1[n];
    float cs = 0.f;
    #pragma unroll
    for (int fm=0; fm<2; ++fm)
      #pragma unroll
      for (int jj=0; jj<4; ++jj)
        cs += fmaxf(acc[fm][fn][jj] + bb, 0.f);
    cs += __shfl_xor(cs, 16);
    cs += __shfl_xor(cs, 32);
    if (q == 0) zsum_p[((mblk&3)*2 + wr)*8192 + b*256 + n] = cs;
  }
}

// ---- final: out[b,:] = (Σ slots zsum)[b,:] @ Wr2 + N*br2. 32 blocks ----
__global__ __launch_bounds__(256) void k_fin(const float* __restrict__ zsum_p,
    const float* __restrict__ Wr2, const float* __restrict__ br2,
    float* __restrict__ out){
  int b = blockIdx.x, t = threadIdx.x;
  __shared__ float zs[256];
  float z = 0.f;
  #pragma unroll
  for (int sl=0; sl<8; ++sl) z += zsum_p[sl*8192 + b*256 + t];
  zs[t] = z; __syncthreads();
  float acc = 0.f;
  #pragma unroll 8
  for (int k=0;k<256;++k) acc = fmaf(zs[k], Wr2[(size_t)k*256 + t], acc);
  out[b*256 + t] = acc + 256.0f*br2[t];
}

extern "C" void kernel_launch(void* const* d_in, const int* in_sizes, int n_in,
                              void* d_out, int out_size, void* d_ws, size_t ws_size,
                              hipStream_t stream){
  (void)in_sizes; (void)n_in; (void)out_size; (void)ws_size;
  const float* jets  = (const float*)d_in[0];
  const float* W_emb = (const float*)d_in[1];
  const float* b_emb = (const float*)d_in[2];
  const float* w_edge= (const float*)d_in[3];
  // d_in[4] = b_edge: cancels in softmax
  const float* W_msg = (const float*)d_in[5];
  const float* b_msg = (const float*)d_in[6];
  const float* Wi    = (const float*)d_in[7];
  const float* bi    = (const float*)d_in[8];
  const float* Wh    = (const float*)d_in[9];
  const float* bh    = (const float*)d_in[10];
  const float* Wr1   = (const float*)d_in[11];
  const float* br1   = (const float*)d_in[12];
  const float* Wr2   = (const float*)d_in[13];
  const float* br2   = (const float*)d_in[14];
  float* out = (float*)d_out;
  float* ws  = (float*)d_ws;
  // workspace layout (float-slot units)
  ushort_t* hbf0  = (ushort_t*)ws;                  // 1,048,576 f
  ushort_t* hbf1  = (ushort_t*)(ws + 1048576);      // 1,048,576 f
  ushort_t* gjets = (ushort_t*)(ws + 2097152);      // 3,145,728 f
  float* WiMt     = ws + 5242880;                   // 196,608 (f32 [k=256][row=768])
  ushort_t* WhB   = (ushort_t*)(ws + 5439488);      // 98,304 f
  ushort_t* Wr1T  = (ushort_t*)(ws + 5537792);      // 32,768 f
  float* s_part   = ws + 5570560;                   // [8][8192]
  float* msg_p    = ws + 5636096;                   // [8][8192]
  float* gmsg_p   = ws + 5701632;                   // [8][24576]
  float* zsum_p   = ws + 5898240;                   // [8][8192] (end 5,963,776 f = 23.9MB)
  ushort_t* hbf[2] = {hbf0, hbf1};

  k_pe<<<512,NT,0,stream>>>(jets, W_emb, b_emb, w_edge, Wi, bi, Wh, Wr1,
                            hbf[0], gjets, WiMt, WhB, Wr1T, s_part);
  for (int it=0; it<3; ++it){
    int cur = it & 1, nxt = cur ^ 1;
    k_hm<<<256,NT,0,stream>>>(hbf[cur], s_part, W_msg, msg_p);
    k_gmsgp<<<256,NT,0,stream>>>(msg_p, b_msg, WiMt, gmsg_p);
    k_gru_mfma<<<512,NT,0,stream>>>(hbf[cur], WhB, bh, gjets, gmsg_p, w_edge,
                                    hbf[nxt], s_part, (it<2)?1:0);
  }
  k_ro<<<512,NT,0,stream>>>(hbf[1], Wr1T, br1, zsum_p);
  k_fin<<<32,NT,0,stream>>>(zsum_p, Wr2, br2, out);
}

// Round 14
// 113.173 us; speedup vs baseline: 24.6379x; 1.3535x over previous
//
#include <hip/hip_runtime.h>
#include <math.h>

#define NT 256
#define APITCH 40

typedef __attribute__((ext_vector_type(8))) short short8;
typedef __attribute__((ext_vector_type(4))) float f32x4;
typedef unsigned short ushort_t;

__device__ __forceinline__ float sigmoidf_(float x){ return 1.0f/(1.0f+__expf(-x)); }
__device__ __forceinline__ ushort_t f2bf(float x){
  unsigned int u = __float_as_uint(x);
  u = u + 0x7fff + ((u>>16)&1);
  return (ushort_t)(u>>16);
}
__device__ __forceinline__ float bf2f(ushort_t b){
  return __uint_as_float(((unsigned int)b)<<16);
}

// ---- PE: weight prep (grid-stride) + embed (16 rows/block). 512 blocks. ----
__global__ __launch_bounds__(256) void k_pe(
    const float* __restrict__ jets, const float* __restrict__ W_emb,
    const float* __restrict__ b_emb, const float* __restrict__ w_edge,
    const float* __restrict__ Wi, const float* __restrict__ Wh,
    const float* __restrict__ Wr1,
    ushort_t* __restrict__ hbf0, float* __restrict__ WiMt,
    ushort_t* __restrict__ WhB, ushort_t* __restrict__ Wr1T,
    float* __restrict__ s_part)
{
  int t = threadIdx.x, blk = blockIdx.x;
  int gid = blk*NT + t, gstride = gridDim.x*NT;
  for (int e=gid; e<256*768; e+=gstride){ int k=e/768, row=e-k*768; WiMt[e]=Wi[(size_t)row*264 + k]; }
  for (int e=gid; e<768*256; e+=gstride){ WhB[e]=f2bf(Wh[e]); }
  for (int e=gid; e<256*256; e+=gstride){ int n=e>>8, k=e&255; Wr1T[e]=f2bf(Wr1[(size_t)k*256+n]); }
  int lane = t & 63, w = t >> 6;
  #pragma unroll
  for (int v=0; v<4; ++v){
    int m = blk*16 + w*4 + v;
    float jr[8];
    #pragma unroll
    for (int f=0; f<8; ++f) jr[f] = jets[m*8+f];
    float sp = 0.f;
    #pragma unroll
    for (int u=0; u<4; ++u){
      int c = lane + 64*u;
      float a = b_emb[c];
      #pragma unroll
      for (int f=0; f<8; ++f) a = fmaf(jr[f], W_emb[f*256+c], a);
      float hv = tanhf(a);
      hbf0[(size_t)m*256 + c] = f2bf(hv);
      sp = fmaf(hv, w_edge[c], sp);
    }
    sp += __shfl_xor(sp,1); sp += __shfl_xor(sp,2); sp += __shfl_xor(sp,4);
    sp += __shfl_xor(sp,8); sp += __shfl_xor(sp,16); sp += __shfl_xor(sp,32);
    if (lane==0) s_part[m] = sp;
    else if (lane<8) s_part[lane*8192 + m] = 0.f;
  }
}

// ---- hbar partials: 256 blocks = (batch, j-chunk); writes its own slot ----
__global__ __launch_bounds__(256) void k_hbar(const ushort_t* __restrict__ hbf,
    const float* __restrict__ s_part, float* __restrict__ hbar_p){
  int t = threadIdx.x;
  int b = blockIdx.x >> 3, js = blockIdx.x & 7;
  int jc = js << 5;
  __shared__ float eS[256], red[256];
  float s_t = 0.f;
  #pragma unroll
  for (int sl=0; sl<8; ++sl) s_t += s_part[sl*8192 + b*256 + t];
  red[t] = s_t; __syncthreads();
  for (int o=128;o>0;o>>=1){ if (t<o) red[t]=fmaxf(red[t],red[t+o]); __syncthreads(); }
  float mx = red[0]; __syncthreads();
  float e = __expf(s_t-mx); eS[t]=e; red[t]=e; __syncthreads();
  for (int o=128;o>0;o>>=1){ if (t<o) red[t]+=red[t+o]; __syncthreads(); }
  float rZ = 1.0f/red[0];
  const ushort_t* hb = hbf + (size_t)b*256*256;
  float p = 0.f;
  #pragma unroll
  for (int j=0;j<32;++j)
    p = fmaf(eS[jc+j], bf2f(hb[(size_t)(jc+j)*256 + t]), p);
  hbar_p[js*8192 + b*256 + t] = p*rZ;
}

// ---- msg partials: 256 blocks = (batch, k-slice of 32). f32, coalesced ----
__global__ __launch_bounds__(256) void k_msgp(const float* __restrict__ hbar_p,
    const float* __restrict__ W_msg, float* __restrict__ msg_p){
  int t = threadIdx.x;
  int b = blockIdx.x >> 3, ks = blockIdx.x & 7;
  __shared__ float hch[32];
  if (t < 32){
    float v = 0.f;
    #pragma unroll
    for (int sl=0; sl<8; ++sl) v += hbar_p[sl*8192 + b*256 + ks*32 + t];
    hch[t] = v;
  }
  __syncthreads();
  float acc = 0.f;
  #pragma unroll
  for (int k=0; k<32; ++k)
    acc = fmaf(hch[k], W_msg[(size_t)(ks*32+k)*256 + t], acc);
  msg_p[ks*8192 + b*256 + t] = acc;
}

// ---- gmsg partials: 256 blocks = (batch, k-slice). mv=tanh(sum+bias) local ----
__global__ __launch_bounds__(256) void k_gmsgp(const float* __restrict__ msg_p,
    const float* __restrict__ b_msg, const float* __restrict__ WiMt,
    float* __restrict__ gmsg_p){
  int t = threadIdx.x;
  int b = blockIdx.x >> 3, ks = blockIdx.x & 7;
  __shared__ float mch[32];
  if (t < 32){
    float v = b_msg[ks*32 + t];
    #pragma unroll
    for (int sl=0; sl<8; ++sl) v += msg_p[sl*8192 + b*256 + ks*32 + t];
    mch[t] = tanhf(v);
  }
  __syncthreads();
  float a0=0.f, a1=0.f, a2=0.f;
  #pragma unroll
  for (int k=0; k<32; ++k){
    float m = mch[k];
    const float* wr = &WiMt[(size_t)(ks*32+k)*768 + t];
    a0 = fmaf(m, wr[0],   a0);
    a1 = fmaf(m, wr[256], a1);
    a2 = fmaf(m, wr[512], a2);
  }
  float* gp = &gmsg_p[(size_t)ks*24576 + (size_t)b*768 + t];
  gp[0] = a0; gp[256] = a1; gp[512] = a2;
}

// ---- GRU via MFMA + fused epilogue; gjets recomputed in-register (rank-8).
//      512 blocks. ----
__global__ __launch_bounds__(256) void k_gru_mfma(
    const ushort_t* __restrict__ hbf_in,
    const ushort_t* __restrict__ WhB, const float* __restrict__ bh,
    const float* __restrict__ bi, const float* __restrict__ jets,
    const float* __restrict__ Wi, const float* __restrict__ gmsg_p,
    const float* __restrict__ w_edge,
    ushort_t* __restrict__ hbf_out, float* __restrict__ s_part, int compute_s)
{
  __shared__ __align__(16) short As[64*APITCH];
  __shared__ __align__(16) short Bs[3*64*APITCH];
  __shared__ float gm_s[192], bh_s[192], bi_s[192];
  __shared__ float jetS[64][9];
  __shared__ float wijS[192][9];
  int t = threadIdx.x;
  int hcb = blockIdx.x & 3, mblk = blockIdx.x >> 2;
  int m0 = mblk*64, hc0 = hcb*64, b = m0 >> 8;
  if (t < 192){
    int g = t>>6, c = t&63;
    int rowi = g*256 + hc0 + c;
    float acc = 0.f;
    #pragma unroll
    for (int sl=0; sl<8; ++sl) acc += gmsg_p[(size_t)sl*24576 + (size_t)b*768 + rowi];
    gm_s[t] = acc;
    bh_s[t] = bh[rowi];
    bi_s[t] = bi[rowi];
  }
  // stage jets rows (64x8, contiguous 2KB) and WiJ strip (192x8)
  for (int e = t; e < 512; e += NT){
    int mr = e >> 3, f = e & 7;
    jetS[mr][f] = jets[(size_t)(m0+mr)*8 + f];
  }
  for (int e = t; e < 1536; e += NT){
    int rr = e >> 3, f = e & 7;
    int rowi = (rr>>6)*256 + hc0 + (rr&63);
    wijS[rr][f] = Wi[(size_t)rowi*264 + 256 + f];
  }
  int lane = t & 63, w = t >> 6;
  int wr = w >> 1, wc = w & 1;
  int q = lane >> 4, r = lane & 15;
  int srow = t >> 2, sseg = t & 3;
  f32x4 acc[3][2][2] = {};
  for (int kt = 0; kt < 8; ++kt){
    __syncthreads();
    *(uint4*)&As[srow*APITCH + sseg*8] = *(const uint4*)&hbf_in[(size_t)(m0+srow)*256 + kt*32 + sseg*8];
    #pragma unroll
    for (int g = 0; g < 3; ++g)
      *(uint4*)&Bs[g*64*APITCH + srow*APITCH + sseg*8] = *(const uint4*)&WhB[(size_t)(g*256 + hc0 + srow)*256 + kt*32 + sseg*8];
    __syncthreads();
    short8 af[2], bfr[3][2];
    #pragma unroll
    for (int fm=0; fm<2; ++fm)
      af[fm] = *(const short8*)&As[(wr*32 + fm*16 + r)*APITCH + q*8];
    #pragma unroll
    for (int g=0; g<3; ++g)
      #pragma unroll
      for (int fn=0; fn<2; ++fn)
        bfr[g][fn] = *(const short8*)&Bs[g*64*APITCH + (wc*32 + fn*16 + r)*APITCH + q*8];
    #pragma unroll
    for (int g=0; g<3; ++g)
      #pragma unroll
      for (int fm=0; fm<2; ++fm)
        #pragma unroll
        for (int fn=0; fn<2; ++fn)
          acc[g][fm][fn] = __builtin_amdgcn_mfma_f32_16x16x32_bf16(af[fm], bfr[g][fn], acc[g][fm][fn], 0,0,0);
  }
  float wef[2];
  wef[0] = w_edge[hc0 + wc*32 + r];
  wef[1] = w_edge[hc0 + wc*32 + 16 + r];
  float pacc[2][4] = {};
  #pragma unroll
  for (int fm=0; fm<2; ++fm)
    #pragma unroll
    for (int fn=0; fn<2; ++fn){
      int cloc = wc*32 + fn*16 + r;
      int hcol = hc0 + cloc;
      #pragma unroll
      for (int jj=0; jj<4; ++jj){
        int mloc = wr*32 + fm*16 + q*4 + jj;
        int m = m0 + mloc;
        // gjets recompute: jd_g = jets[m,:8] . WiJ[g*256+hcol, :8]
        float jd0=0.f, jd1=0.f, jd2=0.f;
        #pragma unroll
        for (int f=0; f<8; ++f){
          float jv = jetS[mloc][f];
          jd0 = fmaf(jv, wijS[cloc][f],       jd0);
          jd1 = fmaf(jv, wijS[64 + cloc][f],  jd1);
          jd2 = fmaf(jv, wijS[128 + cloc][f], jd2);
        }
        float gir = jd0 + bi_s[cloc]     + gm_s[cloc];
        float giz = jd1 + bi_s[64+cloc]  + gm_s[64+cloc];
        float gin = jd2 + bi_s[128+cloc] + gm_s[128+cloc];
        float rr = sigmoidf_(gir + acc[0][fm][fn][jj] + bh_s[cloc]);
        float zz = sigmoidf_(giz + acc[1][fm][fn][jj] + bh_s[64+cloc]);
        float nn = tanhf(gin + rr*(acc[2][fm][fn][jj] + bh_s[128+cloc]));
        float ho = bf2f(hbf_in[(size_t)m*256 + hcol]);
        float hn = (1.f - zz)*nn + zz*ho;
        hbf_out[(size_t)m*256 + hcol] = f2bf(hn);
        pacc[fm][jj] = fmaf(wef[fn], hn, pacc[fm][jj]);
      }
    }
  if (compute_s){
    #pragma unroll
    for (int fm=0; fm<2; ++fm)
      #pragma unroll
      for (int jj=0; jj<4; ++jj){
        float p = pacc[fm][jj];
        p += __shfl_xor(p,1); p += __shfl_xor(p,2);
        p += __shfl_xor(p,4); p += __shfl_xor(p,8);
        if (r == 0)
          s_part[(hcb*2 + wc)*8192 + m0 + wr*32 + fm*16 + q*4 + jj] = p;
      }
  }
}

// ---- readout MFMA: slot partial writes. 512 blocks ----
__global__ __launch_bounds__(256) void k_ro(
    const ushort_t* __restrict__ hbf, const ushort_t* __restrict__ Wr1T,
    const float* __restrict__ br1, float* __restrict__ zsum_p)
{
  __shared__ __align__(16) short As[64*APITCH];
  __shared__ __align__(16) short Bs[64*APITCH];
  int t = threadIdx.x;
  int ncb = blockIdx.x & 3, mblk = blockIdx.x >> 2;
  int m0 = mblk*64, nc0 = ncb*64, b = m0 >> 8;
  int lane = t & 63, w = t >> 6;
  int wr = w >> 1, wc = w & 1;
  int q = lane >> 4, r = lane & 15;
  int srow = t >> 2, sseg = t & 3;
  f32x4 acc[2][2] = {};
  for (int kt = 0; kt < 8; ++kt){
    __syncthreads();
    *(uint4*)&As[srow*APITCH + sseg*8] = *(const uint4*)&hbf[(size_t)(m0+srow)*256 + kt*32 + sseg*8];
    *(uint4*)&Bs[srow*APITCH + sseg*8] = *(const uint4*)&Wr1T[(size_t)(nc0+srow)*256 + kt*32 + sseg*8];
    __syncthreads();
    short8 af[2], bfr[2];
    #pragma unroll
    for (int fm=0; fm<2; ++fm)
      af[fm] = *(const short8*)&As[(wr*32 + fm*16 + r)*APITCH + q*8];
    #pragma unroll
    for (int fn=0; fn<2; ++fn)
      bfr[fn] = *(const short8*)&Bs[(wc*32 + fn*16 + r)*APITCH + q*8];
    #pragma unroll
    for (int fm=0; fm<2; ++fm)
      #pragma unroll
      for (int fn=0; fn<2; ++fn)
        acc[fm][fn] = __builtin_amdgcn_mfma_f32_16x16x32_bf16(af[fm], bfr[fn], acc[fm][fn], 0,0,0);
  }
  #pragma unroll
  for (int fn=0; fn<2; ++fn){
    int n = nc0 + wc*32 + fn*16 + r;
    float bb = br1[n];
    float cs = 0.f;
    #pragma unroll
    for (int fm=0; fm<2; ++fm)
      #pragma unroll
      for (int jj=0; jj<4; ++jj)
        cs += fmaxf(acc[fm][fn][jj] + bb, 0.f);
    cs += __shfl_xor(cs, 16);
    cs += __shfl_xor(cs, 32);
    if (q == 0) zsum_p[((mblk&3)*2 + wr)*8192 + b*256 + n] = cs;
  }
}

// ---- final: out[b,:] = (Σ slots zsum)[b,:] @ Wr2 + N*br2. 32 blocks ----
__global__ __launch_bounds__(256) void k_fin(const float* __restrict__ zsum_p,
    const float* __restrict__ Wr2, const float* __restrict__ br2,
    float* __restrict__ out){
  int b = blockIdx.x, t = threadIdx.x;
  __shared__ float zs[256];
  float z = 0.f;
  #pragma unroll
  for (int sl=0; sl<8; ++sl) z += zsum_p[sl*8192 + b*256 + t];
  zs[t] = z; __syncthreads();
  float acc = 0.f;
  #pragma unroll 8
  for (int k=0;k<256;++k) acc = fmaf(zs[k], Wr2[(size_t)k*256 + t], acc);
  out[b*256 + t] = acc + 256.0f*br2[t];
}

extern "C" void kernel_launch(void* const* d_in, const int* in_sizes, int n_in,
                              void* d_out, int out_size, void* d_ws, size_t ws_size,
                              hipStream_t stream){
  (void)in_sizes; (void)n_in; (void)out_size; (void)ws_size;
  const float* jets  = (const float*)d_in[0];
  const float* W_emb = (const float*)d_in[1];
  const float* b_emb = (const float*)d_in[2];
  const float* w_edge= (const float*)d_in[3];
  // d_in[4] = b_edge: cancels in softmax
  const float* W_msg = (const float*)d_in[5];
  const float* b_msg = (const float*)d_in[6];
  const float* Wi    = (const float*)d_in[7];
  const float* bi    = (const float*)d_in[8];
  const float* Wh    = (const float*)d_in[9];
  const float* bh    = (const float*)d_in[10];
  const float* Wr1   = (const float*)d_in[11];
  const float* br1   = (const float*)d_in[12];
  const float* Wr2   = (const float*)d_in[13];
  const float* br2   = (const float*)d_in[14];
  float* out = (float*)d_out;
  float* ws  = (float*)d_ws;
  // workspace layout (float-slot units)
  ushort_t* hbf0  = (ushort_t*)ws;                  // 1,048,576 f
  ushort_t* hbf1  = (ushort_t*)(ws + 1048576);      // 1,048,576 f
  float* WiMt     = ws + 2097152;                   // 196,608 (f32 [k=256][row=768])
  ushort_t* WhB   = (ushort_t*)(ws + 2293760);      // 98,304 f
  ushort_t* Wr1T  = (ushort_t*)(ws + 2392064);      // 32,768 f
  float* s_part   = ws + 2424832;                   // [8][8192]
  float* hbar_p   = ws + 2490368;                   // [8][8192]
  float* msg_p    = ws + 2555904;                   // [8][8192]
  float* gmsg_p   = ws + 2621440;                   // [8][24576]
  float* zsum_p   = ws + 2818048;                   // [8][8192] (end 2,883,584 f = 11.5MB)
  ushort_t* hbf[2] = {hbf0, hbf1};

  k_pe<<<512,NT,0,stream>>>(jets, W_emb, b_emb, w_edge, Wi, Wh, Wr1,
                            hbf[0], WiMt, WhB, Wr1T, s_part);
  for (int it=0; it<3; ++it){
    int cur = it & 1, nxt = cur ^ 1;
    k_hbar<<<256,NT,0,stream>>>(hbf[cur], s_part, hbar_p);
    k_msgp<<<256,NT,0,stream>>>(hbar_p, W_msg, msg_p);
    k_gmsgp<<<256,NT,0,stream>>>(msg_p, b_msg, WiMt, gmsg_p);
    k_gru_mfma<<<512,NT,0,stream>>>(hbf[cur], WhB, bh, bi, jets, Wi, gmsg_p,
                                    w_edge, hbf[nxt], s_part, (it<2)?1:0);
  }
  k_ro<<<512,NT,0,stream>>>(hbf[1], Wr1T, br1, zsum_p);
  k_fin<<<32,NT,0,stream>>>(zsum_p, Wr2, br2, out);
}

// Round 15
// 108.825 us; speedup vs baseline: 25.6223x; 1.0400x over previous
//
#include <hip/hip_runtime.h>
#include <math.h>

#define NT 256
#define APITCH 40

typedef __attribute__((ext_vector_type(8))) short short8;
typedef __attribute__((ext_vector_type(4))) float f32x4;
typedef unsigned short ushort_t;

__device__ __forceinline__ float sigmoidf_(float x){ return 1.0f/(1.0f+__expf(-x)); }
__device__ __forceinline__ ushort_t f2bf(float x){
  unsigned int u = __float_as_uint(x);
  u = u + 0x7fff + ((u>>16)&1);
  return (ushort_t)(u>>16);
}
__device__ __forceinline__ float bf2f(ushort_t b){
  return __uint_as_float(((unsigned int)b)<<16);
}

// ---- PE: weight prep (grid-stride) + embed (16 rows/block). 512 blocks. ----
__global__ __launch_bounds__(256) void k_pe(
    const float* __restrict__ jets, const float* __restrict__ W_emb,
    const float* __restrict__ b_emb, const float* __restrict__ w_edge,
    const float* __restrict__ Wi, const float* __restrict__ Wh,
    const float* __restrict__ Wr1,
    ushort_t* __restrict__ hbf0, float* __restrict__ WiMt,
    ushort_t* __restrict__ WhB, ushort_t* __restrict__ Wr1T,
    float* __restrict__ s_part)
{
  int t = threadIdx.x, blk = blockIdx.x;
  int gid = blk*NT + t, gstride = gridDim.x*NT;
  for (int e=gid; e<256*768; e+=gstride){ int k=e/768, row=e-k*768; WiMt[e]=Wi[(size_t)row*264 + k]; }
  for (int e=gid; e<768*256; e+=gstride){ WhB[e]=f2bf(Wh[e]); }
  for (int e=gid; e<256*256; e+=gstride){ int n=e>>8, k=e&255; Wr1T[e]=f2bf(Wr1[(size_t)k*256+n]); }
  int lane = t & 63, w = t >> 6;
  #pragma unroll
  for (int v=0; v<4; ++v){
    int m = blk*16 + w*4 + v;
    float jr[8];
    #pragma unroll
    for (int f=0; f<8; ++f) jr[f] = jets[m*8+f];
    float sp = 0.f;
    #pragma unroll
    for (int u=0; u<4; ++u){
      int c = lane + 64*u;
      float a = b_emb[c];
      #pragma unroll
      for (int f=0; f<8; ++f) a = fmaf(jr[f], W_emb[f*256+c], a);
      float hv = tanhf(a);
      hbf0[(size_t)m*256 + c] = f2bf(hv);
      sp = fmaf(hv, w_edge[c], sp);
    }
    sp += __shfl_xor(sp,1); sp += __shfl_xor(sp,2); sp += __shfl_xor(sp,4);
    sp += __shfl_xor(sp,8); sp += __shfl_xor(sp,16); sp += __shfl_xor(sp,32);
    if (lane==0) s_part[m] = sp;
    else if (lane<8) s_part[lane*8192 + m] = 0.f;
  }
}

// ---- hbar partials: 256 blocks = (batch, j-chunk); writes its own slot ----
__global__ __launch_bounds__(256) void k_hbar(const ushort_t* __restrict__ hbf,
    const float* __restrict__ s_part, float* __restrict__ hbar_p){
  int t = threadIdx.x;
  int b = blockIdx.x >> 3, js = blockIdx.x & 7;
  int jc = js << 5;
  __shared__ float eS[256], red[256];
  float s_t = 0.f;
  #pragma unroll
  for (int sl=0; sl<8; ++sl) s_t += s_part[sl*8192 + b*256 + t];
  red[t] = s_t; __syncthreads();
  for (int o=128;o>0;o>>=1){ if (t<o) red[t]=fmaxf(red[t],red[t+o]); __syncthreads(); }
  float mx = red[0]; __syncthreads();
  float e = __expf(s_t-mx); eS[t]=e; red[t]=e; __syncthreads();
  for (int o=128;o>0;o>>=1){ if (t<o) red[t]+=red[t+o]; __syncthreads(); }
  float rZ = 1.0f/red[0];
  const ushort_t* hb = hbf + (size_t)b*256*256;
  float p = 0.f;
  #pragma unroll
  for (int j=0;j<32;++j)
    p = fmaf(eS[jc+j], bf2f(hb[(size_t)(jc+j)*256 + t]), p);
  hbar_p[js*8192 + b*256 + t] = p*rZ;
}

// ---- msgg: full-hbar staged; msg col-slice (32KB W_msg slice, same traffic
//      as old k_msgp); tanh; gmsg partial slot. 256 blocks = (batch, ks). ----
__global__ __launch_bounds__(256) void k_msgg(const float* __restrict__ hbar_p,
    const float* __restrict__ W_msg, const float* __restrict__ b_msg,
    const float* __restrict__ WiMt, float* __restrict__ gmsg_p){
  int t = threadIdx.x;
  int b = blockIdx.x >> 3, ks = blockIdx.x & 7;
  __shared__ float hbS[256];
  __shared__ float red2[8][33];
  __shared__ float mch[32];
  // full hbar for batch b (sum of 8 slots; 8KB coalesced)
  float v = 0.f;
  #pragma unroll
  for (int sl=0; sl<8; ++sl) v += hbar_p[sl*8192 + b*256 + t];
  hbS[t] = v;
  __syncthreads();
  // msg slice c = ks*32+cl: 8 k-segments x 32 cols, coalesced W_msg reads
  int cl = t & 31, kseg = t >> 5;
  float a = 0.f;
  #pragma unroll
  for (int k0=0; k0<32; ++k0){
    int k = kseg*32 + k0;
    a = fmaf(hbS[k], W_msg[(size_t)k*256 + ks*32 + cl], a);
  }
  red2[kseg][cl] = a;
  __syncthreads();
  if (t < 32){
    float m = b_msg[ks*32 + t];
    #pragma unroll
    for (int s2=0; s2<8; ++s2) m += red2[s2][t];
    mch[t] = tanhf(m);
  }
  __syncthreads();
  // gmsg partial for this k-slice (as old k_gmsgp)
  float a0=0.f, a1=0.f, a2=0.f;
  #pragma unroll
  for (int k=0; k<32; ++k){
    float m = mch[k];
    const float* wr = &WiMt[(size_t)(ks*32+k)*768 + t];
    a0 = fmaf(m, wr[0],   a0);
    a1 = fmaf(m, wr[256], a1);
    a2 = fmaf(m, wr[512], a2);
  }
  float* gp = &gmsg_p[(size_t)ks*24576 + (size_t)b*768 + t];
  gp[0] = a0; gp[256] = a1; gp[512] = a2;
}

// ---- GRU via MFMA + fused epilogue; gjets recomputed in-register (rank-8).
//      512 blocks. ----
__global__ __launch_bounds__(256) void k_gru_mfma(
    const ushort_t* __restrict__ hbf_in,
    const ushort_t* __restrict__ WhB, const float* __restrict__ bh,
    const float* __restrict__ bi, const float* __restrict__ jets,
    const float* __restrict__ Wi, const float* __restrict__ gmsg_p,
    const float* __restrict__ w_edge,
    ushort_t* __restrict__ hbf_out, float* __restrict__ s_part, int compute_s)
{
  __shared__ __align__(16) short As[64*APITCH];
  __shared__ __align__(16) short Bs[3*64*APITCH];
  __shared__ float gm_s[192], bh_s[192], bi_s[192];
  __shared__ float jetS[64][9];
  __shared__ float wijS[192][9];
  int t = threadIdx.x;
  int hcb = blockIdx.x & 3, mblk = blockIdx.x >> 2;
  int m0 = mblk*64, hc0 = hcb*64, b = m0 >> 8;
  if (t < 192){
    int g = t>>6, c = t&63;
    int rowi = g*256 + hc0 + c;
    float acc = 0.f;
    #pragma unroll
    for (int sl=0; sl<8; ++sl) acc += gmsg_p[(size_t)sl*24576 + (size_t)b*768 + rowi];
    gm_s[t] = acc;
    bh_s[t] = bh[rowi];
    bi_s[t] = bi[rowi];
  }
  // stage jets rows (64x8, contiguous 2KB) and WiJ strip (192x8)
  for (int e = t; e < 512; e += NT){
    int mr = e >> 3, f = e & 7;
    jetS[mr][f] = jets[(size_t)(m0+mr)*8 + f];
  }
  for (int e = t; e < 1536; e += NT){
    int rr = e >> 3, f = e & 7;
    int rowi = (rr>>6)*256 + hc0 + (rr&63);
    wijS[rr][f] = Wi[(size_t)rowi*264 + 256 + f];
  }
  int lane = t & 63, w = t >> 6;
  int wr = w >> 1, wc = w & 1;
  int q = lane >> 4, r = lane & 15;
  int srow = t >> 2, sseg = t & 3;
  f32x4 acc[3][2][2] = {};
  for (int kt = 0; kt < 8; ++kt){
    __syncthreads();
    *(uint4*)&As[srow*APITCH + sseg*8] = *(const uint4*)&hbf_in[(size_t)(m0+srow)*256 + kt*32 + sseg*8];
    #pragma unroll
    for (int g = 0; g < 3; ++g)
      *(uint4*)&Bs[g*64*APITCH + srow*APITCH + sseg*8] = *(const uint4*)&WhB[(size_t)(g*256 + hc0 + srow)*256 + kt*32 + sseg*8];
    __syncthreads();
    short8 af[2], bfr[3][2];
    #pragma unroll
    for (int fm=0; fm<2; ++fm)
      af[fm] = *(const short8*)&As[(wr*32 + fm*16 + r)*APITCH + q*8];
    #pragma unroll
    for (int g=0; g<3; ++g)
      #pragma unroll
      for (int fn=0; fn<2; ++fn)
        bfr[g][fn] = *(const short8*)&Bs[g*64*APITCH + (wc*32 + fn*16 + r)*APITCH + q*8];
    #pragma unroll
    for (int g=0; g<3; ++g)
      #pragma unroll
      for (int fm=0; fm<2; ++fm)
        #pragma unroll
        for (int fn=0; fn<2; ++fn)
          acc[g][fm][fn] = __builtin_amdgcn_mfma_f32_16x16x32_bf16(af[fm], bfr[g][fn], acc[g][fm][fn], 0,0,0);
  }
  float wef[2];
  wef[0] = w_edge[hc0 + wc*32 + r];
  wef[1] = w_edge[hc0 + wc*32 + 16 + r];
  float pacc[2][4] = {};
  #pragma unroll
  for (int fm=0; fm<2; ++fm)
    #pragma unroll
    for (int fn=0; fn<2; ++fn){
      int cloc = wc*32 + fn*16 + r;
      int hcol = hc0 + cloc;
      #pragma unroll
      for (int jj=0; jj<4; ++jj){
        int mloc = wr*32 + fm*16 + q*4 + jj;
        int m = m0 + mloc;
        // gjets recompute: jd_g = jets[m,:8] . WiJ[g*256+hcol, :8]
        float jd0=0.f, jd1=0.f, jd2=0.f;
        #pragma unroll
        for (int f=0; f<8; ++f){
          float jv = jetS[mloc][f];
          jd0 = fmaf(jv, wijS[cloc][f],       jd0);
          jd1 = fmaf(jv, wijS[64 + cloc][f],  jd1);
          jd2 = fmaf(jv, wijS[128 + cloc][f], jd2);
        }
        float gir = jd0 + bi_s[cloc]     + gm_s[cloc];
        float giz = jd1 + bi_s[64+cloc]  + gm_s[64+cloc];
        float gin = jd2 + bi_s[128+cloc] + gm_s[128+cloc];
        float rr = sigmoidf_(gir + acc[0][fm][fn][jj] + bh_s[cloc]);
        float zz = sigmoidf_(giz + acc[1][fm][fn][jj] + bh_s[64+cloc]);
        float nn = tanhf(gin + rr*(acc[2][fm][fn][jj] + bh_s[128+cloc]));
        float ho = bf2f(hbf_in[(size_t)m*256 + hcol]);
        float hn = (1.f - zz)*nn + zz*ho;
        hbf_out[(size_t)m*256 + hcol] = f2bf(hn);
        pacc[fm][jj] = fmaf(wef[fn], hn, pacc[fm][jj]);
      }
    }
  if (compute_s){
    #pragma unroll
    for (int fm=0; fm<2; ++fm)
      #pragma unroll
      for (int jj=0; jj<4; ++jj){
        float p = pacc[fm][jj];
        p += __shfl_xor(p,1); p += __shfl_xor(p,2);
        p += __shfl_xor(p,4); p += __shfl_xor(p,8);
        if (r == 0)
          s_part[(hcb*2 + wc)*8192 + m0 + wr*32 + fm*16 + q*4 + jj] = p;
      }
  }
}

// ---- readout MFMA: slot partial writes. 512 blocks ----
__global__ __launch_bounds__(256) void k_ro(
    const ushort_t* __restrict__ hbf, const ushort_t* __restrict__ Wr1T,
    const float* __restrict__ br1, float* __restrict__ zsum_p)
{
  __shared__ __align__(16) short As[64*APITCH];
  __shared__ __align__(16) short Bs[64*APITCH];
  int t = threadIdx.x;
  int ncb = blockIdx.x & 3, mblk = blockIdx.x >> 2;
  int m0 = mblk*64, nc0 = ncb*64, b = m0 >> 8;
  int lane = t & 63, w = t >> 6;
  int wr = w >> 1, wc = w & 1;
  int q = lane >> 4, r = lane & 15;
  int srow = t >> 2, sseg = t & 3;
  f32x4 acc[2][2] = {};
  for (int kt = 0; kt < 8; ++kt){
    __syncthreads();
    *(uint4*)&As[srow*APITCH + sseg*8] = *(const uint4*)&hbf[(size_t)(m0+srow)*256 + kt*32 + sseg*8];
    *(uint4*)&Bs[srow*APITCH + sseg*8] = *(const uint4*)&Wr1T[(size_t)(nc0+srow)*256 + kt*32 + sseg*8];
    __syncthreads();
    short8 af[2], bfr[2];
    #pragma unroll
    for (int fm=0; fm<2; ++fm)
      af[fm] = *(const short8*)&As[(wr*32 + fm*16 + r)*APITCH + q*8];
    #pragma unroll
    for (int fn=0; fn<2; ++fn)
      bfr[fn] = *(const short8*)&Bs[(wc*32 + fn*16 + r)*APITCH + q*8];
    #pragma unroll
    for (int fm=0; fm<2; ++fm)
      #pragma unroll
      for (int fn=0; fn<2; ++fn)
        acc[fm][fn] = __builtin_amdgcn_mfma_f32_16x16x32_bf16(af[fm], bfr[fn], acc[fm][fn], 0,0,0);
  }
  #pragma unroll
  for (int fn=0; fn<2; ++fn){
    int n = nc0 + wc*32 + fn*16 + r;
    float bb = br1[n];
    float cs = 0.f;
    #pragma unroll
    for (int fm=0; fm<2; ++fm)
      #pragma unroll
      for (int jj=0; jj<4; ++jj)
        cs += fmaxf(acc[fm][fn][jj] + bb, 0.f);
    cs += __shfl_xor(cs, 16);
    cs += __shfl_xor(cs, 32);
    if (q == 0) zsum_p[((mblk&3)*2 + wr)*8192 + b*256 + n] = cs;
  }
}

// ---- final: out[b,:] = (Σ slots zsum)[b,:] @ Wr2 + N*br2. 32 blocks ----
__global__ __launch_bounds__(256) void k_fin(const float* __restrict__ zsum_p,
    const float* __restrict__ Wr2, const float* __restrict__ br2,
    float* __restrict__ out){
  int b = blockIdx.x, t = threadIdx.x;
  __shared__ float zs[256];
  float z = 0.f;
  #pragma unroll
  for (int sl=0; sl<8; ++sl) z += zsum_p[sl*8192 + b*256 + t];
  zs[t] = z; __syncthreads();
  float acc = 0.f;
  #pragma unroll 8
  for (int k=0;k<256;++k) acc = fmaf(zs[k], Wr2[(size_t)k*256 + t], acc);
  out[b*256 + t] = acc + 256.0f*br2[t];
}

extern "C" void kernel_launch(void* const* d_in, const int* in_sizes, int n_in,
                              void* d_out, int out_size, void* d_ws, size_t ws_size,
                              hipStream_t stream){
  (void)in_sizes; (void)n_in; (void)out_size; (void)ws_size;
  const float* jets  = (const float*)d_in[0];
  const float* W_emb = (const float*)d_in[1];
  const float* b_emb = (const float*)d_in[2];
  const float* w_edge= (const float*)d_in[3];
  // d_in[4] = b_edge: cancels in softmax
  const float* W_msg = (const float*)d_in[5];
  const float* b_msg = (const float*)d_in[6];
  const float* Wi    = (const float*)d_in[7];
  const float* bi    = (const float*)d_in[8];
  const float* Wh    = (const float*)d_in[9];
  const float* bh    = (const float*)d_in[10];
  const float* Wr1   = (const float*)d_in[11];
  const float* br1   = (const float*)d_in[12];
  const float* Wr2   = (const float*)d_in[13];
  const float* br2   = (const float*)d_in[14];
  float* out = (float*)d_out;
  float* ws  = (float*)d_ws;
  // workspace layout (float-slot units)
  ushort_t* hbf0  = (ushort_t*)ws;                  // 1,048,576 f
  ushort_t* hbf1  = (ushort_t*)(ws + 1048576);      // 1,048,576 f
  float* WiMt     = ws + 2097152;                   // 196,608 (f32 [k=256][row=768])
  ushort_t* WhB   = (ushort_t*)(ws + 2293760);      // 98,304 f
  ushort_t* Wr1T  = (ushort_t*)(ws + 2392064);      // 32,768 f
  float* s_part   = ws + 2424832;                   // [8][8192]
  float* hbar_p   = ws + 2490368;                   // [8][8192]
  float* gmsg_p   = ws + 2555904;                   // [8][24576]
  float* zsum_p   = ws + 2752512;                   // [8][8192] (end 2,818,048 f = 11.3MB)
  ushort_t* hbf[2] = {hbf0, hbf1};

  k_pe<<<512,NT,0,stream>>>(jets, W_emb, b_emb, w_edge, Wi, Wh, Wr1,
                            hbf[0], WiMt, WhB, Wr1T, s_part);
  for (int it=0; it<3; ++it){
    int cur = it & 1, nxt = cur ^ 1;
    k_hbar<<<256,NT,0,stream>>>(hbf[cur], s_part, hbar_p);
    k_msgg<<<256,NT,0,stream>>>(hbar_p, W_msg, b_msg, WiMt, gmsg_p);
    k_gru_mfma<<<512,NT,0,stream>>>(hbf[cur], WhB, bh, bi, jets, Wi, gmsg_p,
                                    w_edge, hbf[nxt], s_part, (it<2)?1:0);
  }
  k_ro<<<512,NT,0,stream>>>(hbf[1], Wr1T, br1, zsum_p);
  k_fin<<<32,NT,0,stream>>>(zsum_p, Wr2, br2, out);
}

// Round 16
// 105.270 us; speedup vs baseline: 26.4876x; 1.0338x over previous
//
#include <hip/hip_runtime.h>
#include <math.h>

#define NT 256
#define BPITCH 72   // 64-col bf16 tile row pitch: 36 words = 4 mod 32 -> 2-way (free)

typedef __attribute__((ext_vector_type(8))) short short8;
typedef __attribute__((ext_vector_type(4))) float f32x4;
typedef unsigned short ushort_t;

__device__ __forceinline__ float sigmoidf_(float x){ return 1.0f/(1.0f+__expf(-x)); }
__device__ __forceinline__ ushort_t f2bf(float x){
  unsigned int u = __float_as_uint(x);
  u = u + 0x7fff + ((u>>16)&1);
  return (ushort_t)(u>>16);
}
__device__ __forceinline__ float bf2f(ushort_t b){
  return __uint_as_float(((unsigned int)b)<<16);
}

// ---- PE: weight prep (grid-stride) + embed (16 rows/block). 512 blocks. ----
__global__ __launch_bounds__(256) void k_pe(
    const float* __restrict__ jets, const float* __restrict__ W_emb,
    const float* __restrict__ b_emb, const float* __restrict__ w_edge,
    const float* __restrict__ Wi, const float* __restrict__ Wh,
    const float* __restrict__ Wr1,
    ushort_t* __restrict__ hbf0, float* __restrict__ WiMt,
    ushort_t* __restrict__ WhB, ushort_t* __restrict__ Wr1T,
    float* __restrict__ s_part)
{
  int t = threadIdx.x, blk = blockIdx.x;
  int gid = blk*NT + t, gstride = gridDim.x*NT;
  for (int e=gid; e<256*768; e+=gstride){ int k=e/768, row=e-k*768; WiMt[e]=Wi[(size_t)row*264 + k]; }
  for (int e=gid; e<768*256; e+=gstride){ WhB[e]=f2bf(Wh[e]); }
  for (int e=gid; e<256*256; e+=gstride){ int n=e>>8, k=e&255; Wr1T[e]=f2bf(Wr1[(size_t)k*256+n]); }
  int lane = t & 63, w = t >> 6;
  #pragma unroll
  for (int v=0; v<4; ++v){
    int m = blk*16 + w*4 + v;
    float jr[8];
    #pragma unroll
    for (int f=0; f<8; ++f) jr[f] = jets[m*8+f];
    float sp = 0.f;
    #pragma unroll
    for (int u=0; u<4; ++u){
      int c = lane + 64*u;
      float a = b_emb[c];
      #pragma unroll
      for (int f=0; f<8; ++f) a = fmaf(jr[f], W_emb[f*256+c], a);
      float hv = tanhf(a);
      hbf0[(size_t)m*256 + c] = f2bf(hv);
      sp = fmaf(hv, w_edge[c], sp);
    }
    sp += __shfl_xor(sp,1); sp += __shfl_xor(sp,2); sp += __shfl_xor(sp,4);
    sp += __shfl_xor(sp,8); sp += __shfl_xor(sp,16); sp += __shfl_xor(sp,32);
    if (lane==0) s_part[m] = sp;
    else if (lane<8) s_part[lane*8192 + m] = 0.f;
  }
}

// ---- hbar partials: 256 blocks = (batch, j-chunk); writes its own slot ----
__global__ __launch_bounds__(256) void k_hbar(const ushort_t* __restrict__ hbf,
    const float* __restrict__ s_part, float* __restrict__ hbar_p){
  int t = threadIdx.x;
  int b = blockIdx.x >> 3, js = blockIdx.x & 7;
  int jc = js << 5;
  __shared__ float eS[256], red[256];
  float s_t = 0.f;
  #pragma unroll
  for (int sl=0; sl<8; ++sl) s_t += s_part[sl*8192 + b*256 + t];
  red[t] = s_t; __syncthreads();
  for (int o=128;o>0;o>>=1){ if (t<o) red[t]=fmaxf(red[t],red[t+o]); __syncthreads(); }
  float mx = red[0]; __syncthreads();
  float e = __expf(s_t-mx); eS[t]=e; red[t]=e; __syncthreads();
  for (int o=128;o>0;o>>=1){ if (t<o) red[t]+=red[t+o]; __syncthreads(); }
  float rZ = 1.0f/red[0];
  const ushort_t* hb = hbf + (size_t)b*256*256;
  float p = 0.f;
  #pragma unroll
  for (int j=0;j<32;++j)
    p = fmaf(eS[jc+j], bf2f(hb[(size_t)(jc+j)*256 + t]), p);
  hbar_p[js*8192 + b*256 + t] = p*rZ;
}

// ---- msgg: full-hbar staged; msg col-slice; tanh; gmsg partial slot.
//      256 blocks = (batch, ks). ----
__global__ __launch_bounds__(256) void k_msgg(const float* __restrict__ hbar_p,
    const float* __restrict__ W_msg, const float* __restrict__ b_msg,
    const float* __restrict__ WiMt, float* __restrict__ gmsg_p){
  int t = threadIdx.x;
  int b = blockIdx.x >> 3, ks = blockIdx.x & 7;
  __shared__ float hbS[256];
  __shared__ float red2[8][33];
  __shared__ float mch[32];
  float v = 0.f;
  #pragma unroll
  for (int sl=0; sl<8; ++sl) v += hbar_p[sl*8192 + b*256 + t];
  hbS[t] = v;
  __syncthreads();
  int cl = t & 31, kseg = t >> 5;
  float a = 0.f;
  #pragma unroll
  for (int k0=0; k0<32; ++k0){
    int k = kseg*32 + k0;
    a = fmaf(hbS[k], W_msg[(size_t)k*256 + ks*32 + cl], a);
  }
  red2[kseg][cl] = a;
  __syncthreads();
  if (t < 32){
    float m = b_msg[ks*32 + t];
    #pragma unroll
    for (int s2=0; s2<8; ++s2) m += red2[s2][t];
    mch[t] = tanhf(m);
  }
  __syncthreads();
  float a0=0.f, a1=0.f, a2=0.f;
  #pragma unroll
  for (int k=0; k<32; ++k){
    float m = mch[k];
    const float* wr = &WiMt[(size_t)(ks*32+k)*768 + t];
    a0 = fmaf(m, wr[0],   a0);
    a1 = fmaf(m, wr[256], a1);
    a2 = fmaf(m, wr[512], a2);
  }
  float* gp = &gmsg_p[(size_t)ks*24576 + (size_t)b*768 + t];
  gp[0] = a0; gp[256] = a1; gp[512] = a2;
}

// ---- GRU via MFMA (BK=64, 4 kt steps) + fused epilogue; gjets rank-8
//      recompute. 512 blocks. ----
__global__ __launch_bounds__(256) void k_gru_mfma(
    const ushort_t* __restrict__ hbf_in,
    const ushort_t* __restrict__ WhB, const float* __restrict__ bh,
    const float* __restrict__ bi, const float* __restrict__ jets,
    const float* __restrict__ Wi, const float* __restrict__ gmsg_p,
    const float* __restrict__ w_edge,
    ushort_t* __restrict__ hbf_out, float* __restrict__ s_part, int compute_s)
{
  __shared__ __align__(16) short As[64*BPITCH];
  __shared__ __align__(16) short Bs[3*64*BPITCH];
  __shared__ float gm_s[192], bh_s[192], bi_s[192];
  __shared__ float jetS[64][9];
  __shared__ float wijS[192][9];
  int t = threadIdx.x;
  int hcb = blockIdx.x & 3, mblk = blockIdx.x >> 2;
  int m0 = mblk*64, hc0 = hcb*64, b = m0 >> 8;
  if (t < 192){
    int g = t>>6, c = t&63;
    int rowi = g*256 + hc0 + c;
    float acc = 0.f;
    #pragma unroll
    for (int sl=0; sl<8; ++sl) acc += gmsg_p[(size_t)sl*24576 + (size_t)b*768 + rowi];
    gm_s[t] = acc;
    bh_s[t] = bh[rowi];
    bi_s[t] = bi[rowi];
  }
  for (int e = t; e < 512; e += NT){
    int mr = e >> 3, f = e & 7;
    jetS[mr][f] = jets[(size_t)(m0+mr)*8 + f];
  }
  for (int e = t; e < 1536; e += NT){
    int rr = e >> 3, f = e & 7;
    int rowi = (rr>>6)*256 + hc0 + (rr&63);
    wijS[rr][f] = Wi[(size_t)rowi*264 + 256 + f];
  }
  int lane = t & 63, w = t >> 6;
  int wr = w >> 1, wc = w & 1;
  int q = lane >> 4, r = lane & 15;
  int srow = t >> 2, sseg = t & 3;
  f32x4 acc[3][2][2] = {};
  for (int kt = 0; kt < 4; ++kt){
    __syncthreads();
    *(uint4*)&As[srow*BPITCH + sseg*16]     = *(const uint4*)&hbf_in[(size_t)(m0+srow)*256 + kt*64 + sseg*16];
    *(uint4*)&As[srow*BPITCH + sseg*16 + 8] = *(const uint4*)&hbf_in[(size_t)(m0+srow)*256 + kt*64 + sseg*16 + 8];
    #pragma unroll
    for (int g = 0; g < 3; ++g){
      *(uint4*)&Bs[g*64*BPITCH + srow*BPITCH + sseg*16]     = *(const uint4*)&WhB[(size_t)(g*256 + hc0 + srow)*256 + kt*64 + sseg*16];
      *(uint4*)&Bs[g*64*BPITCH + srow*BPITCH + sseg*16 + 8] = *(const uint4*)&WhB[(size_t)(g*256 + hc0 + srow)*256 + kt*64 + sseg*16 + 8];
    }
    __syncthreads();
    #pragma unroll
    for (int ks2 = 0; ks2 < 2; ++ks2){
      short8 af[2], bfr[3][2];
      #pragma unroll
      for (int fm=0; fm<2; ++fm)
        af[fm] = *(const short8*)&As[(wr*32 + fm*16 + r)*BPITCH + ks2*32 + q*8];
      #pragma unroll
      for (int g=0; g<3; ++g)
        #pragma unroll
        for (int fn=0; fn<2; ++fn)
          bfr[g][fn] = *(const short8*)&Bs[g*64*BPITCH + (wc*32 + fn*16 + r)*BPITCH + ks2*32 + q*8];
      #pragma unroll
      for (int g=0; g<3; ++g)
        #pragma unroll
        for (int fm=0; fm<2; ++fm)
          #pragma unroll
          for (int fn=0; fn<2; ++fn)
            acc[g][fm][fn] = __builtin_amdgcn_mfma_f32_16x16x32_bf16(af[fm], bfr[g][fn], acc[g][fm][fn], 0,0,0);
    }
  }
  float wef[2];
  wef[0] = w_edge[hc0 + wc*32 + r];
  wef[1] = w_edge[hc0 + wc*32 + 16 + r];
  float pacc[2][4] = {};
  #pragma unroll
  for (int fm=0; fm<2; ++fm)
    #pragma unroll
    for (int fn=0; fn<2; ++fn){
      int cloc = wc*32 + fn*16 + r;
      int hcol = hc0 + cloc;
      #pragma unroll
      for (int jj=0; jj<4; ++jj){
        int mloc = wr*32 + fm*16 + q*4 + jj;
        int m = m0 + mloc;
        float jd0=0.f, jd1=0.f, jd2=0.f;
        #pragma unroll
        for (int f=0; f<8; ++f){
          float jv = jetS[mloc][f];
          jd0 = fmaf(jv, wijS[cloc][f],       jd0);
          jd1 = fmaf(jv, wijS[64 + cloc][f],  jd1);
          jd2 = fmaf(jv, wijS[128 + cloc][f], jd2);
        }
        float gir = jd0 + bi_s[cloc]     + gm_s[cloc];
        float giz = jd1 + bi_s[64+cloc]  + gm_s[64+cloc];
        float gin = jd2 + bi_s[128+cloc] + gm_s[128+cloc];
        float rr = sigmoidf_(gir + acc[0][fm][fn][jj] + bh_s[cloc]);
        float zz = sigmoidf_(giz + acc[1][fm][fn][jj] + bh_s[64+cloc]);
        float nn = tanhf(gin + rr*(acc[2][fm][fn][jj] + bh_s[128+cloc]));
        float ho = bf2f(hbf_in[(size_t)m*256 + hcol]);
        float hn = (1.f - zz)*nn + zz*ho;
        hbf_out[(size_t)m*256 + hcol] = f2bf(hn);
        pacc[fm][jj] = fmaf(wef[fn], hn, pacc[fm][jj]);
      }
    }
  if (compute_s){
    #pragma unroll
    for (int fm=0; fm<2; ++fm)
      #pragma unroll
      for (int jj=0; jj<4; ++jj){
        float p = pacc[fm][jj];
        p += __shfl_xor(p,1); p += __shfl_xor(p,2);
        p += __shfl_xor(p,4); p += __shfl_xor(p,8);
        if (r == 0)
          s_part[(hcb*2 + wc)*8192 + m0 + wr*32 + fm*16 + q*4 + jj] = p;
      }
  }
}

// ---- readout MFMA (BK=64): slot partial writes. 512 blocks ----
__global__ __launch_bounds__(256) void k_ro(
    const ushort_t* __restrict__ hbf, const ushort_t* __restrict__ Wr1T,
    const float* __restrict__ br1, float* __restrict__ zsum_p)
{
  __shared__ __align__(16) short As[64*BPITCH];
  __shared__ __align__(16) short Bs[64*BPITCH];
  int t = threadIdx.x;
  int ncb = blockIdx.x & 3, mblk = blockIdx.x >> 2;
  int m0 = mblk*64, nc0 = ncb*64, b = m0 >> 8;
  int lane = t & 63, w = t >> 6;
  int wr = w >> 1, wc = w & 1;
  int q = lane >> 4, r = lane & 15;
  int srow = t >> 2, sseg = t & 3;
  f32x4 acc[2][2] = {};
  for (int kt = 0; kt < 4; ++kt){
    __syncthreads();
    *(uint4*)&As[srow*BPITCH + sseg*16]     = *(const uint4*)&hbf[(size_t)(m0+srow)*256 + kt*64 + sseg*16];
    *(uint4*)&As[srow*BPITCH + sseg*16 + 8] = *(const uint4*)&hbf[(size_t)(m0+srow)*256 + kt*64 + sseg*16 + 8];
    *(uint4*)&Bs[srow*BPITCH + sseg*16]     = *(const uint4*)&Wr1T[(size_t)(nc0+srow)*256 + kt*64 + sseg*16];
    *(uint4*)&Bs[srow*BPITCH + sseg*16 + 8] = *(const uint4*)&Wr1T[(size_t)(nc0+srow)*256 + kt*64 + sseg*16 + 8];
    __syncthreads();
    #pragma unroll
    for (int ks2 = 0; ks2 < 2; ++ks2){
      short8 af[2], bfr[2];
      #pragma unroll
      for (int fm=0; fm<2; ++fm)
        af[fm] = *(const short8*)&As[(wr*32 + fm*16 + r)*BPITCH + ks2*32 + q*8];
      #pragma unroll
      for (int fn=0; fn<2; ++fn)
        bfr[fn] = *(const short8*)&Bs[(wc*32 + fn*16 + r)*BPITCH + ks2*32 + q*8];
      #pragma unroll
      for (int fm=0; fm<2; ++fm)
        #pragma unroll
        for (int fn=0; fn<2; ++fn)
          acc[fm][fn] = __builtin_amdgcn_mfma_f32_16x16x32_bf16(af[fm], bfr[fn], acc[fm][fn], 0,0,0);
    }
  }
  #pragma unroll
  for (int fn=0; fn<2; ++fn){
    int n = nc0 + wc*32 + fn*16 + r;
    float bb = br1[n];
    float cs = 0.f;
    #pragma unroll
    for (int fm=0; fm<2; ++fm)
      #pragma unroll
      for (int jj=0; jj<4; ++jj)
        cs += fmaxf(acc[fm][fn][jj] + bb, 0.f);
    cs += __shfl_xor(cs, 16);
    cs += __shfl_xor(cs, 32);
    if (q == 0) zsum_p[((mblk&3)*2 + wr)*8192 + b*256 + n] = cs;
  }
}

// ---- final: out[b,:] = (Σ slots zsum)[b,:] @ Wr2 + N*br2. 32 blocks ----
__global__ __launch_bounds__(256) void k_fin(const float* __restrict__ zsum_p,
    const float* __restrict__ Wr2, const float* __restrict__ br2,
    float* __restrict__ out){
  int b = blockIdx.x, t = threadIdx.x;
  __shared__ float zs[256];
  float z = 0.f;
  #pragma unroll
  for (int sl=0; sl<8; ++sl) z += zsum_p[sl*8192 + b*256 + t];
  zs[t] = z; __syncthreads();
  float acc = 0.f;
  #pragma unroll 8
  for (int k=0;k<256;++k) acc = fmaf(zs[k], Wr2[(size_t)k*256 + t], acc);
  out[b*256 + t] = acc + 256.0f*br2[t];
}

extern "C" void kernel_launch(void* const* d_in, const int* in_sizes, int n_in,
                              void* d_out, int out_size, void* d_ws, size_t ws_size,
                              hipStream_t stream){
  (void)in_sizes; (void)n_in; (void)out_size; (void)ws_size;
  const float* jets  = (const float*)d_in[0];
  const float* W_emb = (const float*)d_in[1];
  const float* b_emb = (const float*)d_in[2];
  const float* w_edge= (const float*)d_in[3];
  // d_in[4] = b_edge: cancels in softmax
  const float* W_msg = (const float*)d_in[5];
  const float* b_msg = (const float*)d_in[6];
  const float* Wi    = (const float*)d_in[7];
  const float* bi    = (const float*)d_in[8];
  const float* Wh    = (const float*)d_in[9];
  const float* bh    = (const float*)d_in[10];
  const float* Wr1   = (const float*)d_in[11];
  const float* br1   = (const float*)d_in[12];
  const float* Wr2   = (const float*)d_in[13];
  const float* br2   = (const float*)d_in[14];
  float* out = (float*)d_out;
  float* ws  = (float*)d_ws;
  // workspace layout (float-slot units)
  ushort_t* hbf0  = (ushort_t*)ws;                  // 1,048,576 f
  ushort_t* hbf1  = (ushort_t*)(ws + 1048576);      // 1,048,576 f
  float* WiMt     = ws + 2097152;                   // 196,608 (f32 [k=256][row=768])
  ushort_t* WhB   = (ushort_t*)(ws + 2293760);      // 98,304 f
  ushort_t* Wr1T  = (ushort_t*)(ws + 2392064);      // 32,768 f
  float* s_part   = ws + 2424832;                   // [8][8192]
  float* hbar_p   = ws + 2490368;                   // [8][8192]
  float* gmsg_p   = ws + 2555904;                   // [8][24576]
  float* zsum_p   = ws + 2752512;                   // [8][8192] (end 2,818,048 f = 11.3MB)
  ushort_t* hbf[2] = {hbf0, hbf1};

  k_pe<<<512,NT,0,stream>>>(jets, W_emb, b_emb, w_edge, Wi, Wh, Wr1,
                            hbf[0], WiMt, WhB, Wr1T, s_part);
  for (int it=0; it<3; ++it){
    int cur = it & 1, nxt = cur ^ 1;
    k_hbar<<<256,NT,0,stream>>>(hbf[cur], s_part, hbar_p);
    k_msgg<<<256,NT,0,stream>>>(hbar_p, W_msg, b_msg, WiMt, gmsg_p);
    k_gru_mfma<<<512,NT,0,stream>>>(hbf[cur], WhB, bh, bi, jets, Wi, gmsg_p,
                                    w_edge, hbf[nxt], s_part, (it<2)?1:0);
  }
  k_ro<<<512,NT,0,stream>>>(hbf[1], Wr1T, br1, zsum_p);
  k_fin<<<32,NT,0,stream>>>(zsum_p, Wr2, br2, out);
}